// Round 1
// baseline (1476.055 us; speedup 1.0000x reference)
//
#include <hip/hip_runtime.h>
#include <hip/hip_bf16.h>

#define N_NODES 100000
#define N_EDGES 1600000

// ---------------------------------------------------------------------------
// CSR row_ptr via binary search over sorted edge_row
// ---------------------------------------------------------------------------
__global__ void build_row_ptr(const int* __restrict__ row, int* __restrict__ rp) {
    int n = blockIdx.x * blockDim.x + threadIdx.x;
    if (n > N_NODES) return;
    // first index i with row[i] >= n
    int lo = 0, hi = N_EDGES;
    while (lo < hi) {
        int mid = (lo + hi) >> 1;
        if (row[mid] < n) lo = mid + 1; else hi = mid;
    }
    rp[n] = lo;
}

// ---------------------------------------------------------------------------
// SpMM: agg[r][f] = sum_{e in row r} val[e] * x[col[e]][f]
// one wave (64 lanes) per node; lanes stride the feature dim
// ---------------------------------------------------------------------------
template<int F, int ACC>
__global__ __launch_bounds__(256) void spmm_kernel(
    const float* __restrict__ xin, const int* __restrict__ rp,
    const int* __restrict__ col, const float* __restrict__ val,
    float* __restrict__ agg)
{
    int wave = threadIdx.x >> 6;
    int lane = threadIdx.x & 63;
    int node = blockIdx.x * (blockDim.x >> 6) + wave;
    if (node >= N_NODES) return;
    int e0 = rp[node], e1 = rp[node + 1];
    float acc[ACC];
#pragma unroll
    for (int i = 0; i < ACC; i++) acc[i] = 0.f;
    for (int e = e0; e < e1; e++) {
        int c = col[e];
        float v = val[e];
        const float* xr = xin + (long)c * F;
#pragma unroll
        for (int i = 0; i < ACC; i++) {
            int f = lane + 64 * i;
            if (f < F) acc[i] += v * xr[f];
        }
    }
    float* ar = agg + (long)node * F;
#pragma unroll
    for (int i = 0; i < ACC; i++) {
        int f = lane + 64 * i;
        if (f < F) ar[f] = acc[i];
    }
}

// ---------------------------------------------------------------------------
// Fused (dual-)GEMM: C = act( A0@B0 [+ A1@B1] + bias0 [+ bias1] )
// A: M x K row-major (two of them = concat-K), B: K x N row-major.
// BM=BN=64, BK=16, 4x4 microtile, 256 threads.
// Requires K % 4 == 0 (true here: 100,200,128,256).
// ---------------------------------------------------------------------------
#define BM 64
#define BN 64
#define BK 16
#define TM 4
#define TN 4

__global__ __launch_bounds__(256) void gemm_fused(
    const float* __restrict__ A0, const float* __restrict__ A1,
    const float* __restrict__ B0, const float* __restrict__ B1,
    const float* __restrict__ bias0, const float* __restrict__ bias1,
    float* __restrict__ C, int M, int N, int K, int relu)
{
    __shared__ float As[BK][BM + 4];
    __shared__ float Bs[BK][BN + 4];

    const int Ktot = A1 ? 2 * K : K;
    const int tid = threadIdx.x;
    const int tx = tid & 15;        // 0..15 -> column group
    const int ty = tid >> 4;        // 0..15 -> row group
    const int rowBase = blockIdx.y * BM;
    const int colBase = blockIdx.x * BN;

    // A-tile load mapping: 64 rows x 16 k, float4 along k -> 1 float4/thread
    const int aRow = tid >> 2;          // 0..63
    const int aKq  = (tid & 3) * 4;     // 0,4,8,12
    // B-tile load mapping: 16 k-rows x 64 n, float4 along n -> 1 float4/thread
    const int bKrow = tid >> 4;         // 0..15
    const int bNq   = (tid & 15) * 4;   // 0..60

    float acc[TM][TN] = {};

    for (int kk = 0; kk < Ktot; kk += BK) {
        // ---- stage A tile (transposed into LDS) ----
        {
            float4 av = make_float4(0.f, 0.f, 0.f, 0.f);
            int r = rowBase + aRow;
            int k0 = kk + aKq;
            if (r < M && k0 < Ktot) {
                const float* src; int krel;
                if (k0 < K) { src = A0 + (long)r * K; krel = k0; }
                else        { src = A1 + (long)r * K; krel = k0 - K; }
                av = *(const float4*)(src + krel);
            }
            As[aKq + 0][aRow] = av.x;
            As[aKq + 1][aRow] = av.y;
            As[aKq + 2][aRow] = av.z;
            As[aKq + 3][aRow] = av.w;
        }
        // ---- stage B tile ----
        {
            float4 bv = make_float4(0.f, 0.f, 0.f, 0.f);
            int kb = kk + bKrow;
            int n0 = colBase + bNq;
            if (kb < Ktot) {
                const float* src; int krel;
                if (kb < K) { src = B0; krel = kb; }
                else        { src = B1; krel = kb - K; }
                if (n0 + 3 < N) {
                    bv = *(const float4*)(src + (long)krel * N + n0);
                } else {
                    float t0 = (n0 + 0 < N) ? src[(long)krel * N + n0 + 0] : 0.f;
                    float t1 = (n0 + 1 < N) ? src[(long)krel * N + n0 + 1] : 0.f;
                    float t2 = (n0 + 2 < N) ? src[(long)krel * N + n0 + 2] : 0.f;
                    float t3 = (n0 + 3 < N) ? src[(long)krel * N + n0 + 3] : 0.f;
                    bv = make_float4(t0, t1, t2, t3);
                }
            }
            *(float4*)&Bs[bKrow][bNq] = bv;
        }
        __syncthreads();

#pragma unroll
        for (int k = 0; k < BK; k++) {
            float4 av = *(const float4*)&As[k][ty * TM];
            float4 bv = *(const float4*)&Bs[k][tx * TN];
            float a[TM] = {av.x, av.y, av.z, av.w};
            float b[TN] = {bv.x, bv.y, bv.z, bv.w};
#pragma unroll
            for (int m = 0; m < TM; m++)
#pragma unroll
                for (int n = 0; n < TN; n++)
                    acc[m][n] += a[m] * b[n];
        }
        __syncthreads();
    }

    // ---- epilogue: bias + relu + store ----
#pragma unroll
    for (int n = 0; n < TN; n++) {
        int c = colBase + tx * TN + n;
        if (c >= N) continue;
        float bb = bias0 ? bias0[c] : 0.f;
        if (bias1) bb += bias1[c];
#pragma unroll
        for (int m = 0; m < TM; m++) {
            int r = rowBase + ty * TM + m;
            if (r >= M) continue;
            float v = acc[m][n] + bb;
            if (relu) v = fmaxf(v, 0.f);
            C[(long)r * N + c] = v;
        }
    }
}

// ---------------------------------------------------------------------------
// BatchNorm over axis 0 (nodes), 256 columns
// ---------------------------------------------------------------------------
#define BN_ROWS 391   // ceil(100000/256)

__global__ __launch_bounds__(256) void bn_stats(const float* __restrict__ h,
                                                float* __restrict__ stats) {
    int t = threadIdx.x;   // column
    int r0 = blockIdx.x * BN_ROWS;
    int r1 = r0 + BN_ROWS; if (r1 > N_NODES) r1 = N_NODES;
    float s = 0.f, s2 = 0.f;
    for (int r = r0; r < r1; r++) {
        float v = h[(long)r * 256 + t];
        s += v; s2 += v * v;
    }
    atomicAdd(&stats[t], s);
    atomicAdd(&stats[256 + t], s2);
}

__global__ void bn_finalize(float* __restrict__ stats,
                            const float* __restrict__ g,
                            const float* __restrict__ b) {
    int t = threadIdx.x;
    const float invN = 1.f / (float)N_NODES;
    float mu = stats[t] * invN;
    float var = stats[256 + t] * invN - mu * mu;
    float sc = g[t] * rsqrtf(var + 1e-5f);
    stats[512 + t] = sc;
    stats[768 + t] = b[t] - mu * sc;
}

__global__ __launch_bounds__(256) void bn_apply(float* __restrict__ h,
                                                const float* __restrict__ stats) {
    int t = threadIdx.x;
    float sc = stats[512 + t];
    float sh = stats[768 + t];
    int r0 = blockIdx.x * BN_ROWS;
    int r1 = r0 + BN_ROWS; if (r1 > N_NODES) r1 = N_NODES;
    for (int r = r0; r < r1; r++) {
        long i = (long)r * 256 + t;
        h[i] = fmaxf(h[i] * sc + sh, 0.f);
    }
}

// ---------------------------------------------------------------------------
// launch
// ---------------------------------------------------------------------------
extern "C" void kernel_launch(void* const* d_in, const int* in_sizes, int n_in,
                              void* d_out, int out_size, void* d_ws, size_t ws_size,
                              hipStream_t stream) {
    const float* x        = (const float*)d_in[0];
    const int*   edge_row = (const int*)  d_in[1];
    const int*   edge_col = (const int*)  d_in[2];
    const float* edge_val = (const float*)d_in[3];
    const float* gc0_W  = (const float*)d_in[4];
    const float* gc0_b  = (const float*)d_in[5];
    const float* gc0_Ws = (const float*)d_in[6];
    const float* gc0_bs = (const float*)d_in[7];
    const float* gc1_W  = (const float*)d_in[8];
    const float* gc1_b  = (const float*)d_in[9];
    const float* gc1_Ws = (const float*)d_in[10];
    const float* gc1_bs = (const float*)d_in[11];
    const float* gc2_W  = (const float*)d_in[12];
    const float* gc2_b  = (const float*)d_in[13];
    const float* gc2_Ws = (const float*)d_in[14];
    const float* gc2_bs = (const float*)d_in[15];
    const float* fc1_W  = (const float*)d_in[16];
    const float* fc1_b  = (const float*)d_in[17];
    const float* fc2a_W = (const float*)d_in[18];
    const float* fc2a_b = (const float*)d_in[19];
    const float* bn_g   = (const float*)d_in[20];
    const float* bn_b   = (const float*)d_in[21];
    const float* fc2b_W = (const float*)d_in[22];
    const float* fc2b_b = (const float*)d_in[23];
    float* out = (float*)d_out;

    // workspace layout
    char* ws = (char*)d_ws;
    int*   rowptr = (int*)ws;                       // 100001 ints
    float* stats  = (float*)(ws + 416 * 1024);      // 1024 floats
    float* bufA   = (float*)(ws + 416 * 1024 + 4096);                 // 25.6M floats
    float* bufB   = (float*)(ws + 416 * 1024 + 4096 + 102400000);     // 20.0M floats
    float* bufC   = (float*)(ws + 416 * 1024 + 4096 + 102400000 + 80000000); // 12.8M floats

    // CSR
    build_row_ptr<<<(N_NODES + 256) / 256, 256, 0, stream>>>(edge_row, rowptr);

    dim3 blk(256);
    const int nodesPerBlk = 4; // 4 waves/block
    dim3 spmmGrid((N_NODES + nodesPerBlk - 1) / nodesPerBlk);

    // ---- GC layer 0: F 100 -> 200 ----
    spmm_kernel<100, 2><<<spmmGrid, blk, 0, stream>>>(x, rowptr, edge_col, edge_val, bufC);
    {
        dim3 g((200 + BN - 1) / BN, (N_NODES + BM - 1) / BM);
        gemm_fused<<<g, blk, 0, stream>>>(bufC, x, gc0_W, gc0_Ws, gc0_b, gc0_bs,
                                          bufB, N_NODES, 200, 100, 1);
    }
    // ---- GC layer 1: F 200 -> 128 ----
    spmm_kernel<200, 4><<<spmmGrid, blk, 0, stream>>>(bufB, rowptr, edge_col, edge_val, bufA);
    {
        dim3 g((128 + BN - 1) / BN, (N_NODES + BM - 1) / BM);
        gemm_fused<<<g, blk, 0, stream>>>(bufA, bufB, gc1_W, gc1_Ws, gc1_b, gc1_bs,
                                          bufC, N_NODES, 128, 200, 1);
    }
    // ---- GC layer 2: F 128 -> 128 ----
    spmm_kernel<128, 2><<<spmmGrid, blk, 0, stream>>>(bufC, rowptr, edge_col, edge_val, bufB);
    {
        dim3 g((128 + BN - 1) / BN, (N_NODES + BM - 1) / BM);
        gemm_fused<<<g, blk, 0, stream>>>(bufB, bufC, gc2_W, gc2_Ws, gc2_b, gc2_bs,
                                          bufA, N_NODES, 128, 128, 1);
    }
    // ---- fc1: 128 -> 128, relu ----
    {
        dim3 g((128 + BN - 1) / BN, (N_NODES + BM - 1) / BM);
        gemm_fused<<<g, blk, 0, stream>>>(bufA, nullptr, fc1_W, nullptr, fc1_b, nullptr,
                                          bufC, N_NODES, 128, 128, 1);
    }
    // ---- fc2a: 128 -> 256, no relu ----
    {
        dim3 g((256 + BN - 1) / BN, (N_NODES + BM - 1) / BM);
        gemm_fused<<<g, blk, 0, stream>>>(bufC, nullptr, fc2a_W, nullptr, fc2a_b, nullptr,
                                          bufA, N_NODES, 256, 128, 0);
    }
    // ---- batchnorm + relu (in place on bufA) ----
    hipMemsetAsync(stats, 0, 512 * sizeof(float), stream);
    bn_stats<<<256, 256, 0, stream>>>(bufA, stats);
    bn_finalize<<<1, 256, 0, stream>>>(stats, bn_g, bn_b);
    bn_apply<<<256, 256, 0, stream>>>(bufA, stats);
    // ---- fc2b: 256 -> 18 ----
    {
        dim3 g((18 + BN - 1) / BN, (N_NODES + BM - 1) / BM);
        gemm_fused<<<g, blk, 0, stream>>>(bufA, nullptr, fc2b_W, nullptr, fc2b_b, nullptr,
                                          out, N_NODES, 18, 256, 0);
    }
}

// Round 2
// 914.288 us; speedup vs baseline: 1.6144x; 1.6144x over previous
//
#include <hip/hip_runtime.h>

#define N_NODES 100000
#define N_EDGES 1600000

typedef __attribute__((ext_vector_type(8))) short bf16x8;
typedef __attribute__((ext_vector_type(4))) float f32x4;

__device__ __forceinline__ unsigned short f2bf(float f) {
    unsigned u = __float_as_uint(f);
    u = (u + 0x7FFFu + ((u >> 16) & 1u)) >> 16;
    return (unsigned short)u;
}
__device__ __forceinline__ float bf2f(unsigned short h) {
    return __uint_as_float(((unsigned)h) << 16);
}

// ---------------------------------------------------------------------------
// CSR row_ptr via binary search over sorted edge_row
// ---------------------------------------------------------------------------
__global__ void build_row_ptr(const int* __restrict__ row, int* __restrict__ rp) {
    int n = blockIdx.x * blockDim.x + threadIdx.x;
    if (n > N_NODES) return;
    int lo = 0, hi = N_EDGES;
    while (lo < hi) {
        int mid = (lo + hi) >> 1;
        if (row[mid] < n) lo = mid + 1; else hi = mid;
    }
    rp[n] = lo;
}

// ---------------------------------------------------------------------------
// x (fp32, 100k x 100) -> bf16 padded to ld 104 (pad cols zero)
// ---------------------------------------------------------------------------
__global__ __launch_bounds__(128) void conv_x(const float* __restrict__ x,
                                              unsigned short* __restrict__ xb) {
    int r = blockIdx.x;
    int c = threadIdx.x;
    if (c < 104)
        xb[(size_t)r * 104 + c] = (c < 100) ? f2bf(x[(size_t)r * 100 + c]) : (unsigned short)0;
}

// ---------------------------------------------------------------------------
// Weight prep: build bf16 N-major (Bt[n][k]) weight buffers, zero-padded k
// ---------------------------------------------------------------------------
// concat-K: k in [0,Kpad) -> W[k][n] (k<K), k in [Kpad,2Kpad) -> Ws[k-Kpad][n]
__global__ void bt_dualK(const float* __restrict__ W, const float* __restrict__ Ws,
                         int K, int Kpad, int N, int ldk, unsigned short* __restrict__ Bt) {
    int idx = blockIdx.x * blockDim.x + threadIdx.x;
    if (idx >= N * ldk) return;
    int n = idx / ldk, k = idx % ldk;
    float v = 0.f;
    if (k < Kpad) { if (k < K) v = W[(size_t)k * N + n]; }
    else if (k < 2 * Kpad) { int kr = k - Kpad; if (kr < K) v = Ws[(size_t)kr * N + n]; }
    Bt[idx] = f2bf(v);
}
// side-by-side N: n<N0 -> W[k][n], else Ws[k][n-N0]; both K x N0
__global__ void bt_dualN(const float* __restrict__ W, const float* __restrict__ Ws,
                         int K, int N0, int N, int ldk, unsigned short* __restrict__ Bt) {
    int idx = blockIdx.x * blockDim.x + threadIdx.x;
    if (idx >= N * ldk) return;
    int n = idx / ldk, k = idx % ldk;
    float v = 0.f;
    if (k < K) v = (n < N0) ? W[(size_t)k * N0 + n] : Ws[(size_t)k * N0 + (n - N0)];
    Bt[idx] = f2bf(v);
}
__global__ void bt_single(const float* __restrict__ W, int K, int N, int ldk,
                          unsigned short* __restrict__ Bt) {
    int idx = blockIdx.x * blockDim.x + threadIdx.x;
    if (idx >= N * ldk) return;
    int n = idx / ldk, k = idx % ldk;
    Bt[idx] = f2bf((k < K) ? W[(size_t)k * N + n] : 0.f);
}
__global__ void add_bias(const float* __restrict__ a, const float* __restrict__ b,
                         float* __restrict__ dst, int n) {
    int i = blockIdx.x * blockDim.x + threadIdx.x;
    if (i < n) dst[i] = a[i] + b[i];
}

// ---------------------------------------------------------------------------
// SpMM over bf16 feature table: one wave per node, lane holds 2 features.
// F even, F <= 128. out bf16 or fp32.
// ---------------------------------------------------------------------------
__global__ __launch_bounds__(256) void spmm_bf16(
    const unsigned short* __restrict__ xin, int ldin, int F,
    const int* __restrict__ rp, const int* __restrict__ col,
    const float* __restrict__ val, void* __restrict__ outv,
    int ldout, int out_bf16)
{
    int wave = threadIdx.x >> 6, lane = threadIdx.x & 63;
    int node = blockIdx.x * 4 + wave;
    if (node >= N_NODES) return;
    int e0 = rp[node], e1 = rp[node + 1];
    const bool act = (2 * lane) < F;
    float ax = 0.f, ay = 0.f;
    int e = e0;
    for (; e + 2 <= e1; e += 2) {
        int c0 = col[e], c1 = col[e + 1];
        float v0 = val[e], v1 = val[e + 1];
        unsigned u0 = 0, u1 = 0;
        if (act) {
            u0 = *(const unsigned*)(xin + (size_t)c0 * ldin + 2 * lane);
            u1 = *(const unsigned*)(xin + (size_t)c1 * ldin + 2 * lane);
        }
        ax += v0 * __uint_as_float(u0 << 16);
        ay += v0 * __uint_as_float(u0 & 0xFFFF0000u);
        ax += v1 * __uint_as_float(u1 << 16);
        ay += v1 * __uint_as_float(u1 & 0xFFFF0000u);
    }
    if (e < e1) {
        int c0 = col[e];
        float v0 = val[e];
        unsigned u0 = 0;
        if (act) u0 = *(const unsigned*)(xin + (size_t)c0 * ldin + 2 * lane);
        ax += v0 * __uint_as_float(u0 << 16);
        ay += v0 * __uint_as_float(u0 & 0xFFFF0000u);
    }
    if (act) {
        if (out_bf16) {
            unsigned short* o = (unsigned short*)outv + (size_t)node * ldout;
            o[2 * lane] = f2bf(ax);
            o[2 * lane + 1] = f2bf(ay);
        } else {
            float* o = (float*)outv + (size_t)node * ldout;
            o[2 * lane] = ax;
            o[2 * lane + 1] = ay;
        }
    }
}

// ---------------------------------------------------------------------------
// bf16 MFMA GEMM: C = act(concatK(A0,A1) @ B + bias)
// A: M x Ktot bf16 row-major (split at K0 between A0/A1), B: bf16 N-major Bt[n][k].
// Tile 128x128, BK=32, 256 threads (4 waves, each 64x64 via 4x4 16x16x32 MFMAs).
// ldk multiple of 32; K0, Ktot multiples of 8; lda multiples of 8.
// ---------------------------------------------------------------------------
template<int OUTBF>
__global__ __launch_bounds__(256) void gemm_mfma(
    const unsigned short* __restrict__ A0, const unsigned short* __restrict__ A1,
    int lda0, int lda1, int K0, int Ktot,
    const unsigned short* __restrict__ Bt, int ldk,
    const float* __restrict__ bias, void* __restrict__ Cv,
    int M, int N, int ldc, int relu)
{
    __shared__ __align__(16) unsigned short As[128][56];
    __shared__ __align__(16) unsigned short Bs[128][56];

    const int tid = threadIdx.x;
    const int rowBase = blockIdx.y * 128;
    const int colBase = blockIdx.x * 128;
    const int wave = tid >> 6, lane = tid & 63;
    const int wr = (wave >> 1) * 64, wc = (wave & 1) * 64;
    const int lrow = lane & 15, lq = lane >> 4;

    f32x4 acc[4][4] = {};

    for (int kk = 0; kk < ldk; kk += 32) {
#pragma unroll
        for (int i = 0; i < 2; ++i) {
            int c = tid + 256 * i;
            int row = c >> 2;
            int kof = (c & 3) * 8;
            int k0 = kk + kof;
            uint4 av = make_uint4(0, 0, 0, 0);
            int gr = rowBase + row;
            if (gr < M && k0 < Ktot) {
                const unsigned short* src; int krel;
                if (k0 < K0) { src = A0 + (size_t)gr * lda0; krel = k0; }
                else         { src = A1 + (size_t)gr * lda1; krel = k0 - K0; }
                av = *(const uint4*)(src + krel);
            }
            *(uint4*)&As[row][kof] = av;
            uint4 bv = make_uint4(0, 0, 0, 0);
            int n0 = colBase + row;
            if (n0 < N) bv = *(const uint4*)(Bt + (size_t)n0 * ldk + k0);
            *(uint4*)&Bs[row][kof] = bv;
        }
        __syncthreads();

        bf16x8 af[4], bfr[4];
#pragma unroll
        for (int m = 0; m < 4; ++m)
            af[m] = *(const bf16x8*)&As[wr + 16 * m + lrow][lq * 8];
#pragma unroll
        for (int n = 0; n < 4; ++n)
            bfr[n] = *(const bf16x8*)&Bs[wc + 16 * n + lrow][lq * 8];
#pragma unroll
        for (int m = 0; m < 4; ++m)
#pragma unroll
            for (int n = 0; n < 4; ++n)
                acc[m][n] = __builtin_amdgcn_mfma_f32_16x16x32_bf16(af[m], bfr[n], acc[m][n], 0, 0, 0);
        __syncthreads();
    }

#pragma unroll
    for (int m = 0; m < 4; ++m) {
#pragma unroll
        for (int n = 0; n < 4; ++n) {
            int colg = colBase + wc + 16 * n + lrow;
            if (colg >= N) continue;
            float bb = bias ? bias[colg] : 0.f;
#pragma unroll
            for (int r = 0; r < 4; ++r) {
                int rowg = rowBase + wr + 16 * m + lq * 4 + r;
                if (rowg >= M) continue;
                float v = acc[m][n][r] + bb;
                if (relu) v = fmaxf(v, 0.f);
                if (OUTBF) ((unsigned short*)Cv)[(size_t)rowg * ldc + colg] = f2bf(v);
                else       ((float*)Cv)[(size_t)rowg * ldc + colg] = v;
            }
        }
    }
}

// ---------------------------------------------------------------------------
// layer1 combine: h1 = relu(agg1 + z + b + bs), z = yz[:,128:256]
// ---------------------------------------------------------------------------
__global__ __launch_bounds__(256) void add_relu1(
    const float* __restrict__ agg, const unsigned short* __restrict__ yz,
    const float* __restrict__ b, const float* __restrict__ bs,
    unsigned short* __restrict__ h1)
{
    int idx = blockIdx.x * 256 + threadIdx.x;  // over 100000*128
    int r = idx >> 7, c = idx & 127;
    float v = agg[idx] + bf2f(yz[(size_t)r * 256 + 128 + c]) + b[c] + bs[c];
    h1[idx] = f2bf(fmaxf(v, 0.f));
}

// ---------------------------------------------------------------------------
// BatchNorm (256 cols) over bf16 h4 (ld 256), writes bf16 h5 with relu
// ---------------------------------------------------------------------------
#define BN_ROWS 391

__global__ __launch_bounds__(256) void bn_stats(const unsigned short* __restrict__ h,
                                                float* __restrict__ stats) {
    int t = threadIdx.x;
    int r0 = blockIdx.x * BN_ROWS;
    int r1 = r0 + BN_ROWS; if (r1 > N_NODES) r1 = N_NODES;
    float s = 0.f, s2 = 0.f;
    for (int r = r0; r < r1; r++) {
        float v = bf2f(h[(size_t)r * 256 + t]);
        s += v; s2 += v * v;
    }
    atomicAdd(&stats[t], s);
    atomicAdd(&stats[256 + t], s2);
}

__global__ void bn_finalize(float* __restrict__ stats,
                            const float* __restrict__ g,
                            const float* __restrict__ b) {
    int t = threadIdx.x;
    const float invN = 1.f / (float)N_NODES;
    float mu = stats[t] * invN;
    float var = stats[256 + t] * invN - mu * mu;
    float sc = g[t] * rsqrtf(var + 1e-5f);
    stats[512 + t] = sc;
    stats[768 + t] = b[t] - mu * sc;
}

__global__ __launch_bounds__(256) void bn_apply(const unsigned short* __restrict__ h,
                                                const float* __restrict__ stats,
                                                unsigned short* __restrict__ o) {
    int t = threadIdx.x;
    float sc = stats[512 + t];
    float sh = stats[768 + t];
    int r0 = blockIdx.x * BN_ROWS;
    int r1 = r0 + BN_ROWS; if (r1 > N_NODES) r1 = N_NODES;
    for (int r = r0; r < r1; r++) {
        size_t i = (size_t)r * 256 + t;
        o[i] = f2bf(fmaxf(bf2f(h[i]) * sc + sh, 0.f));
    }
}

// ---------------------------------------------------------------------------
// launch
// ---------------------------------------------------------------------------
extern "C" void kernel_launch(void* const* d_in, const int* in_sizes, int n_in,
                              void* d_out, int out_size, void* d_ws, size_t ws_size,
                              hipStream_t stream) {
    const float* x        = (const float*)d_in[0];
    const int*   edge_row = (const int*)  d_in[1];
    const int*   edge_col = (const int*)  d_in[2];
    const float* edge_val = (const float*)d_in[3];
    const float* gc0_W  = (const float*)d_in[4];
    const float* gc0_b  = (const float*)d_in[5];
    const float* gc0_Ws = (const float*)d_in[6];
    const float* gc0_bs = (const float*)d_in[7];
    const float* gc1_W  = (const float*)d_in[8];
    const float* gc1_b  = (const float*)d_in[9];
    const float* gc1_Ws = (const float*)d_in[10];
    const float* gc1_bs = (const float*)d_in[11];
    const float* gc2_W  = (const float*)d_in[12];
    const float* gc2_b  = (const float*)d_in[13];
    const float* gc2_Ws = (const float*)d_in[14];
    const float* gc2_bs = (const float*)d_in[15];
    const float* fc1_W  = (const float*)d_in[16];
    const float* fc1_b  = (const float*)d_in[17];
    const float* fc2a_W = (const float*)d_in[18];
    const float* fc2a_b = (const float*)d_in[19];
    const float* bn_g   = (const float*)d_in[20];
    const float* bn_b   = (const float*)d_in[21];
    const float* fc2b_W = (const float*)d_in[22];
    const float* fc2b_b = (const float*)d_in[23];
    float* out = (float*)d_out;

    char* ws = (char*)d_ws;
    int*   rowptr = (int*)ws;                          // 400 KB
    float* stats  = (float*)(ws + 512 * 1024);         // 4 KB
    size_t o = 520 * 1024;
    unsigned short* Bt0   = (unsigned short*)(ws + o); o += 200 * 224 * 2;
    unsigned short* Bt1   = (unsigned short*)(ws + o); o += 256 * 224 * 2;
    unsigned short* Bt2   = (unsigned short*)(ws + o); o += 128 * 256 * 2;
    unsigned short* Btf1  = (unsigned short*)(ws + o); o += 128 * 128 * 2;
    unsigned short* Btf2a = (unsigned short*)(ws + o); o += 256 * 128 * 2;
    unsigned short* Btf2b = (unsigned short*)(ws + o); o += 18 * 256 * 2;
    float* bias0 = (float*)(ws + o); o += 200 * 4;
    float* bias2 = (float*)(ws + o); o += 128 * 4;
    const size_t SLOT = 52u * 1024 * 1024;
    char* S1 = ws + 1 * 1024 * 1024;
    char* S2 = S1 + SLOT;
    char* S3 = S2 + SLOT;

    unsigned short* xb   = (unsigned short*)S1;  // 100k x 104 bf16
    unsigned short* agg0 = (unsigned short*)S2;  // 100k x 104 bf16
    unsigned short* h0   = (unsigned short*)S3;  // 100k x 200 bf16
    unsigned short* yz   = (unsigned short*)S1;  // 100k x 256 bf16 (y|z)
    float*          agg1 = (float*)S2;           // 100k x 128 fp32
    unsigned short* h1   = (unsigned short*)S3;  // 100k x 128 bf16
    unsigned short* agg2 = (unsigned short*)S2;  // 100k x 128 bf16
    unsigned short* h2   = (unsigned short*)S1;  // 100k x 128 bf16
    unsigned short* h3   = (unsigned short*)S2;  // 100k x 128 bf16
    unsigned short* h4   = (unsigned short*)S3;  // 100k x 256 bf16
    unsigned short* h5   = (unsigned short*)S1;  // 100k x 256 bf16

    // ---- prep ----
    build_row_ptr<<<392, 256, 0, stream>>>(edge_row, rowptr);
    conv_x<<<N_NODES, 128, 0, stream>>>(x, xb);
    bt_dualK<<<(200 * 224 + 255) / 256, 256, 0, stream>>>(gc0_W, gc0_Ws, 100, 104, 200, 224, Bt0);
    bt_dualN<<<(256 * 224 + 255) / 256, 256, 0, stream>>>(gc1_W, gc1_Ws, 200, 128, 256, 224, Bt1);
    bt_dualK<<<(128 * 256 + 255) / 256, 256, 0, stream>>>(gc2_W, gc2_Ws, 128, 128, 128, 256, Bt2);
    bt_single<<<(128 * 128 + 255) / 256, 256, 0, stream>>>(fc1_W, 128, 128, 128, Btf1);
    bt_single<<<(256 * 128 + 255) / 256, 256, 0, stream>>>(fc2a_W, 128, 256, 128, Btf2a);
    bt_single<<<(18 * 256 + 255) / 256, 256, 0, stream>>>(fc2b_W, 256, 18, 256, Btf2b);
    add_bias<<<1, 256, 0, stream>>>(gc0_b, gc0_bs, bias0, 200);
    add_bias<<<1, 256, 0, stream>>>(gc2_b, gc2_bs, bias2, 128);

    const int spmmGrid = (N_NODES + 3) / 4;

    // ---- GC layer 0: SpMM(xb) then dual GEMM [agg0|xb]@[W;Ws] ----
    spmm_bf16<<<spmmGrid, 256, 0, stream>>>(xb, 104, 104, rowptr, edge_col, edge_val, agg0, 104, 1);
    {
        dim3 g(2, (N_NODES + 127) / 128);
        gemm_mfma<1><<<g, 256, 0, stream>>>(agg0, xb, 104, 104, 104, 208, Bt0, 224,
                                            bias0, h0, N_NODES, 200, 200, 1);
    }
    // ---- GC layer 1 (reordered): yz = h0@[W|Ws]; agg1 = SpMM(y); combine ----
    {
        dim3 g(2, (N_NODES + 127) / 128);
        gemm_mfma<1><<<g, 256, 0, stream>>>(h0, h0, 200, 200, 200, 200, Bt1, 224,
                                            nullptr, yz, N_NODES, 256, 256, 0);
    }
    spmm_bf16<<<spmmGrid, 256, 0, stream>>>(yz, 256, 128, rowptr, edge_col, edge_val, agg1, 128, 0);
    add_relu1<<<(N_NODES * 128) / 256, 256, 0, stream>>>(agg1, yz, gc1_b, gc1_bs, h1);
    // ---- GC layer 2: SpMM(h1) then dual GEMM [agg2|h1]@[W;Ws] ----
    spmm_bf16<<<spmmGrid, 256, 0, stream>>>(h1, 128, 128, rowptr, edge_col, edge_val, agg2, 128, 1);
    {
        dim3 g(1, (N_NODES + 127) / 128);
        gemm_mfma<1><<<g, 256, 0, stream>>>(agg2, h1, 128, 128, 128, 256, Bt2, 256,
                                            bias2, h2, N_NODES, 128, 128, 1);
    }
    // ---- fc1 ----
    {
        dim3 g(1, (N_NODES + 127) / 128);
        gemm_mfma<1><<<g, 256, 0, stream>>>(h2, h2, 128, 128, 128, 128, Btf1, 128,
                                            fc1_b, h3, N_NODES, 128, 128, 1);
    }
    // ---- fc2a ----
    {
        dim3 g(2, (N_NODES + 127) / 128);
        gemm_mfma<1><<<g, 256, 0, stream>>>(h3, h3, 128, 128, 128, 128, Btf2a, 128,
                                            fc2a_b, h4, N_NODES, 256, 256, 0);
    }
    // ---- batchnorm + relu ----
    hipMemsetAsync(stats, 0, 512 * sizeof(float), stream);
    bn_stats<<<256, 256, 0, stream>>>(h4, stats);
    bn_finalize<<<1, 256, 0, stream>>>(stats, bn_g, bn_b);
    bn_apply<<<256, 256, 0, stream>>>(h4, stats, h5);
    // ---- fc2b -> out (fp32) ----
    {
        dim3 g(1, (N_NODES + 127) / 128);
        gemm_mfma<0><<<g, 256, 0, stream>>>(h5, h5, 256, 256, 256, 256, Btf2b, 256,
                                            fc2b_b, out, N_NODES, 18, 18, 0);
    }
}

// Round 3
// 803.594 us; speedup vs baseline: 1.8368x; 1.1377x over previous
//
#include <hip/hip_runtime.h>

#define N_NODES 100000
#define N_EDGES 1600000

typedef __attribute__((ext_vector_type(8))) short bf16x8;
typedef __attribute__((ext_vector_type(4))) float f32x4;

__device__ __forceinline__ unsigned short f2bf(float f) {
    unsigned u = __float_as_uint(f);
    u = (u + 0x7FFFu + ((u >> 16) & 1u)) >> 16;
    return (unsigned short)u;
}
__device__ __forceinline__ float bf2f(unsigned short h) {
    return __uint_as_float(((unsigned)h) << 16);
}

// ---------------------------------------------------------------------------
// CSR row_ptr via binary search over sorted edge_row
// ---------------------------------------------------------------------------
__global__ void build_row_ptr(const int* __restrict__ row, int* __restrict__ rp) {
    int n = blockIdx.x * blockDim.x + threadIdx.x;
    if (n > N_NODES) return;
    int lo = 0, hi = N_EDGES;
    while (lo < hi) {
        int mid = (lo + hi) >> 1;
        if (row[mid] < n) lo = mid + 1; else hi = mid;
    }
    rp[n] = lo;
}

// ---------------------------------------------------------------------------
// x (fp32, 100k x 100) -> bf16 padded to ld 104, grid-stride
// ---------------------------------------------------------------------------
__global__ __launch_bounds__(256) void conv_x(const float* __restrict__ x,
                                              unsigned short* __restrict__ xb) {
    const int total = N_NODES * 104;
    for (int i = blockIdx.x * 256 + threadIdx.x; i < total; i += gridDim.x * 256) {
        int r = i / 104, c = i - r * 104;
        xb[i] = (c < 100) ? f2bf(x[(size_t)r * 100 + c]) : (unsigned short)0;
    }
}

// ---------------------------------------------------------------------------
// All weight prep in ONE kernel (flat index over concatenated regions)
// ---------------------------------------------------------------------------
__global__ __launch_bounds__(256) void prep_all(
    const float* __restrict__ gc0W, const float* __restrict__ gc0Ws,
    const float* __restrict__ gc1W, const float* __restrict__ gc1Ws,
    const float* __restrict__ gc2W, const float* __restrict__ gc2Ws,
    const float* __restrict__ f1W,  const float* __restrict__ f2aW,
    const float* __restrict__ f2bW,
    const float* __restrict__ gc0b, const float* __restrict__ gc0bs,
    const float* __restrict__ gc2b, const float* __restrict__ gc2bs,
    unsigned short* __restrict__ Bt0, unsigned short* __restrict__ Bt1,
    unsigned short* __restrict__ Bt2, unsigned short* __restrict__ Btf1,
    unsigned short* __restrict__ Btf2a, unsigned short* __restrict__ Btf2b,
    float* __restrict__ bias0, float* __restrict__ bias2)
{
    int i = blockIdx.x * 256 + threadIdx.x;
    if (i < 44800) {  // Bt0: concat-K (K=100,Kpad=104), N=200, ldk=224
        int n = i / 224, k = i - n * 224; float v = 0.f;
        if (k < 104) { if (k < 100) v = gc0W[(size_t)k * 200 + n]; }
        else { int kr = k - 104; if (kr < 100) v = gc0Ws[(size_t)kr * 200 + n]; }
        Bt0[i] = f2bf(v); return;
    }
    i -= 44800;
    if (i < 57344) {  // Bt1: side-by-side N (K=200, N0=128, N=256), ldk=224
        int n = i / 224, k = i - n * 224; float v = 0.f;
        if (k < 200) v = (n < 128) ? gc1W[(size_t)k * 128 + n] : gc1Ws[(size_t)k * 128 + (n - 128)];
        Bt1[i] = f2bf(v); return;
    }
    i -= 57344;
    if (i < 32768) {  // Bt2: concat-K (K=128), N=128, ldk=256
        int n = i / 256, k = i - n * 256; float v;
        if (k < 128) v = gc2W[(size_t)k * 128 + n];
        else         v = gc2Ws[(size_t)(k - 128) * 128 + n];
        Bt2[i] = f2bf(v); return;
    }
    i -= 32768;
    if (i < 16384) { int n = i >> 7, k = i & 127; Btf1[i] = f2bf(f1W[(size_t)k * 128 + n]); return; }
    i -= 16384;
    if (i < 32768) { int n = i >> 7, k = i & 127; Btf2a[i] = f2bf(f2aW[(size_t)k * 256 + n]); return; }
    i -= 32768;
    if (i < 4608) { int n = i >> 8, k = i & 255; Btf2b[i] = f2bf(f2bW[(size_t)k * 18 + n]); return; }
    i -= 4608;
    if (i < 200) { bias0[i] = gc0b[i] + gc0bs[i]; return; }
    i -= 200;
    if (i < 128) { bias2[i] = gc2b[i] + gc2bs[i]; return; }
}

// ---------------------------------------------------------------------------
// SpMM v3: one wave per node, lane holds 2 bf16 features, 8 gathers in flight.
// FUSE=1: layer-1 epilogue out = relu(agg + z + b0 + b1), z = xin[node][128+f]
// ---------------------------------------------------------------------------
template<int FUSE>
__global__ __launch_bounds__(256) void spmm_v3(
    const unsigned short* __restrict__ xin, int ldin, int F,
    const int* __restrict__ rp, const int* __restrict__ col,
    const float* __restrict__ val,
    const float* __restrict__ b0, const float* __restrict__ b1,
    unsigned short* __restrict__ outp, int ldout)
{
    int wave = threadIdx.x >> 6, lane = threadIdx.x & 63;
    int node = blockIdx.x * 4 + wave;
    if (node >= N_NODES) return;
    int e0 = rp[node], e1 = rp[node + 1];
    const int f = 2 * lane;
    const bool act = f < F;
    const unsigned short* xbase = xin + f;
    float ax = 0.f, ay = 0.f;
    int e = e0;
    for (; e + 8 <= e1; e += 8) {
        int c[8]; float v[8]; unsigned u[8];
#pragma unroll
        for (int j = 0; j < 8; j++) { c[j] = col[e + j]; v[j] = val[e + j]; }
#pragma unroll
        for (int j = 0; j < 8; j++)
            u[j] = act ? *(const unsigned*)(xbase + (size_t)c[j] * ldin) : 0u;
#pragma unroll
        for (int j = 0; j < 8; j++) {
            ax += v[j] * __uint_as_float(u[j] << 16);
            ay += v[j] * __uint_as_float(u[j] & 0xFFFF0000u);
        }
    }
    for (; e < e1; e++) {
        int c0 = col[e]; float v0 = val[e];
        unsigned u0 = act ? *(const unsigned*)(xbase + (size_t)c0 * ldin) : 0u;
        ax += v0 * __uint_as_float(u0 << 16);
        ay += v0 * __uint_as_float(u0 & 0xFFFF0000u);
    }
    if (act) {
        if (FUSE) {
            unsigned uz = *(const unsigned*)(xin + (size_t)node * ldin + 128 + f);
            float zx = __uint_as_float(uz << 16);
            float zy = __uint_as_float(uz & 0xFFFF0000u);
            ax = fmaxf(ax + zx + b0[f] + b1[f], 0.f);
            ay = fmaxf(ay + zy + b0[f + 1] + b1[f + 1], 0.f);
        }
        unsigned pack = ((unsigned)f2bf(ay) << 16) | (unsigned)f2bf(ax);
        *(unsigned*)(outp + (size_t)node * ldout + f) = pack;
    }
}

// ---------------------------------------------------------------------------
// bf16 MFMA GEMM: C = act(concatK(A0,A1) @ B + bias)
// APPLYBN=1: A elements transformed a = relu(a*sc[k]+sh[k]) at staging
// (sc/sh in stats[512..1023]); used for fc2b over BN(h4).
// ---------------------------------------------------------------------------
template<int OUTBF, int APPLYBN>
__global__ __launch_bounds__(256) void gemm_mfma(
    const unsigned short* __restrict__ A0, const unsigned short* __restrict__ A1,
    int lda0, int lda1, int K0, int Ktot,
    const unsigned short* __restrict__ Bt, int ldk,
    const float* __restrict__ bias, void* __restrict__ Cv,
    int M, int N, int ldc, int relu, const float* __restrict__ stats)
{
    __shared__ __align__(16) unsigned short As[128][56];
    __shared__ __align__(16) unsigned short Bs[128][56];

    const int tid = threadIdx.x;
    const int rowBase = blockIdx.y * 128;
    const int colBase = blockIdx.x * 128;
    const int wave = tid >> 6, lane = tid & 63;
    const int wr = (wave >> 1) * 64, wc = (wave & 1) * 64;
    const int lrow = lane & 15, lq = lane >> 4;

    f32x4 acc[4][4] = {};

    for (int kk = 0; kk < ldk; kk += 32) {
#pragma unroll
        for (int i = 0; i < 2; ++i) {
            int c = tid + 256 * i;
            int row = c >> 2;
            int kof = (c & 3) * 8;
            int k0 = kk + kof;
            uint4 av = make_uint4(0, 0, 0, 0);
            int gr = rowBase + row;
            if (gr < M && k0 < Ktot) {
                const unsigned short* src; int krel;
                if (k0 < K0) { src = A0 + (size_t)gr * lda0; krel = k0; }
                else         { src = A1 + (size_t)gr * lda1; krel = k0 - K0; }
                av = *(const uint4*)(src + krel);
                if (APPLYBN) {
                    const float* sc = stats + 512 + k0;
                    const float* sh = stats + 768 + k0;
                    unsigned r[4] = {av.x, av.y, av.z, av.w};
#pragma unroll
                    for (int j = 0; j < 4; j++) {
                        float lo = __uint_as_float(r[j] << 16) * sc[2 * j] + sh[2 * j];
                        float hi = __uint_as_float(r[j] & 0xFFFF0000u) * sc[2 * j + 1] + sh[2 * j + 1];
                        lo = fmaxf(lo, 0.f); hi = fmaxf(hi, 0.f);
                        r[j] = ((unsigned)f2bf(hi) << 16) | (unsigned)f2bf(lo);
                    }
                    av = make_uint4(r[0], r[1], r[2], r[3]);
                }
            }
            *(uint4*)&As[row][kof] = av;
            uint4 bv = make_uint4(0, 0, 0, 0);
            int n0 = colBase + row;
            if (n0 < N) bv = *(const uint4*)(Bt + (size_t)n0 * ldk + k0);
            *(uint4*)&Bs[row][kof] = bv;
        }
        __syncthreads();

        bf16x8 af[4], bfr[4];
#pragma unroll
        for (int m = 0; m < 4; ++m)
            af[m] = *(const bf16x8*)&As[wr + 16 * m + lrow][lq * 8];
#pragma unroll
        for (int n = 0; n < 4; ++n)
            bfr[n] = *(const bf16x8*)&Bs[wc + 16 * n + lrow][lq * 8];
#pragma unroll
        for (int m = 0; m < 4; ++m)
#pragma unroll
            for (int n = 0; n < 4; ++n)
                acc[m][n] = __builtin_amdgcn_mfma_f32_16x16x32_bf16(af[m], bfr[n], acc[m][n], 0, 0, 0);
        __syncthreads();
    }

#pragma unroll
    for (int m = 0; m < 4; ++m) {
#pragma unroll
        for (int n = 0; n < 4; ++n) {
            int colg = colBase + wc + 16 * n + lrow;
            if (colg >= N) continue;
            float bb = bias ? bias[colg] : 0.f;
#pragma unroll
            for (int r = 0; r < 4; ++r) {
                int rowg = rowBase + wr + 16 * m + lq * 4 + r;
                if (rowg >= M) continue;
                float v = acc[m][n][r] + bb;
                if (relu) v = fmaxf(v, 0.f);
                if (OUTBF) ((unsigned short*)Cv)[(size_t)rowg * ldc + colg] = f2bf(v);
                else       ((float*)Cv)[(size_t)rowg * ldc + colg] = v;
            }
        }
    }
}

// ---------------------------------------------------------------------------
// BatchNorm stats (256 cols) over bf16 h4 (ld 256)
// ---------------------------------------------------------------------------
#define BN_ROWS 391

__global__ __launch_bounds__(256) void bn_stats(const unsigned short* __restrict__ h,
                                                float* __restrict__ stats) {
    int t = threadIdx.x;
    int r0 = blockIdx.x * BN_ROWS;
    int r1 = r0 + BN_ROWS; if (r1 > N_NODES) r1 = N_NODES;
    float s = 0.f, s2 = 0.f;
    for (int r = r0; r < r1; r++) {
        float v = bf2f(h[(size_t)r * 256 + t]);
        s += v; s2 += v * v;
    }
    atomicAdd(&stats[t], s);
    atomicAdd(&stats[256 + t], s2);
}

__global__ void bn_finalize(float* __restrict__ stats,
                            const float* __restrict__ g,
                            const float* __restrict__ b) {
    int t = threadIdx.x;
    const float invN = 1.f / (float)N_NODES;
    float mu = stats[t] * invN;
    float var = stats[256 + t] * invN - mu * mu;
    float sc = g[t] * rsqrtf(var + 1e-5f);
    stats[512 + t] = sc;
    stats[768 + t] = b[t] - mu * sc;
}

// ---------------------------------------------------------------------------
// launch
// ---------------------------------------------------------------------------
extern "C" void kernel_launch(void* const* d_in, const int* in_sizes, int n_in,
                              void* d_out, int out_size, void* d_ws, size_t ws_size,
                              hipStream_t stream) {
    const float* x        = (const float*)d_in[0];
    const int*   edge_row = (const int*)  d_in[1];
    const int*   edge_col = (const int*)  d_in[2];
    const float* edge_val = (const float*)d_in[3];
    const float* gc0_W  = (const float*)d_in[4];
    const float* gc0_b  = (const float*)d_in[5];
    const float* gc0_Ws = (const float*)d_in[6];
    const float* gc0_bs = (const float*)d_in[7];
    const float* gc1_W  = (const float*)d_in[8];
    const float* gc1_b  = (const float*)d_in[9];
    const float* gc1_Ws = (const float*)d_in[10];
    const float* gc1_bs = (const float*)d_in[11];
    const float* gc2_W  = (const float*)d_in[12];
    const float* gc2_b  = (const float*)d_in[13];
    const float* gc2_Ws = (const float*)d_in[14];
    const float* gc2_bs = (const float*)d_in[15];
    const float* fc1_W  = (const float*)d_in[16];
    const float* fc1_b  = (const float*)d_in[17];
    const float* fc2a_W = (const float*)d_in[18];
    const float* fc2a_b = (const float*)d_in[19];
    const float* bn_g   = (const float*)d_in[20];
    const float* bn_b   = (const float*)d_in[21];
    const float* fc2b_W = (const float*)d_in[22];
    const float* fc2b_b = (const float*)d_in[23];
    float* out = (float*)d_out;

    char* ws = (char*)d_ws;
    int*   rowptr = (int*)ws;                          // 400 KB
    float* stats  = (float*)(ws + 512 * 1024);         // 4 KB
    size_t o = 520 * 1024;
    unsigned short* Bt0   = (unsigned short*)(ws + o); o += 200 * 224 * 2;
    unsigned short* Bt1   = (unsigned short*)(ws + o); o += 256 * 224 * 2;
    unsigned short* Bt2   = (unsigned short*)(ws + o); o += 128 * 256 * 2;
    unsigned short* Btf1  = (unsigned short*)(ws + o); o += 128 * 128 * 2;
    unsigned short* Btf2a = (unsigned short*)(ws + o); o += 256 * 128 * 2;
    unsigned short* Btf2b = (unsigned short*)(ws + o); o += 18 * 256 * 2;
    float* bias0 = (float*)(ws + o); o += 200 * 4;
    float* bias2 = (float*)(ws + o); o += 128 * 4;
    const size_t SLOT = 52u * 1024 * 1024;
    char* S1 = ws + 1 * 1024 * 1024;
    char* S2 = S1 + SLOT;
    char* S3 = S2 + SLOT;

    unsigned short* xb   = (unsigned short*)S1;  // 100k x 104
    unsigned short* agg0 = (unsigned short*)S2;  // 100k x 104
    unsigned short* h0   = (unsigned short*)S3;  // 100k x 200
    unsigned short* yz   = (unsigned short*)S1;  // 100k x 256 (y|z)
    unsigned short* h1   = (unsigned short*)S2;  // 100k x 128
    unsigned short* agg2 = (unsigned short*)S3;  // 100k x 128
    unsigned short* h2   = (unsigned short*)S1;  // 100k x 128
    unsigned short* h3   = (unsigned short*)S2;  // 100k x 128
    unsigned short* h4   = (unsigned short*)S3;  // 100k x 256

    // ---- prep ----
    build_row_ptr<<<392, 256, 0, stream>>>(edge_row, rowptr);
    conv_x<<<2048, 256, 0, stream>>>(x, xb);
    prep_all<<<(189000 + 255) / 256, 256, 0, stream>>>(
        gc0_W, gc0_Ws, gc1_W, gc1_Ws, gc2_W, gc2_Ws, fc1_W, fc2a_W, fc2b_W,
        gc0_b, gc0_bs, gc2_b, gc2_bs,
        Bt0, Bt1, Bt2, Btf1, Btf2a, Btf2b, bias0, bias2);

    const int spmmGrid = (N_NODES + 3) / 4;

    // ---- GC layer 0 ----
    spmm_v3<0><<<spmmGrid, 256, 0, stream>>>(xb, 104, 104, rowptr, edge_col, edge_val,
                                             nullptr, nullptr, agg0, 104);
    {
        dim3 g(2, (N_NODES + 127) / 128);
        gemm_mfma<1, 0><<<g, 256, 0, stream>>>(agg0, xb, 104, 104, 104, 208, Bt0, 224,
                                               bias0, h0, N_NODES, 200, 200, 1, nullptr);
    }
    // ---- GC layer 1 (GEMM-first): yz = h0@[W|Ws]; h1 = relu(SpMM(y)+z+b+bs) ----
    {
        dim3 g(2, (N_NODES + 127) / 128);
        gemm_mfma<1, 0><<<g, 256, 0, stream>>>(h0, h0, 200, 200, 200, 200, Bt1, 224,
                                               nullptr, yz, N_NODES, 256, 256, 0, nullptr);
    }
    spmm_v3<1><<<spmmGrid, 256, 0, stream>>>(yz, 256, 128, rowptr, edge_col, edge_val,
                                             gc1_b, gc1_bs, h1, 128);
    // ---- GC layer 2 ----
    spmm_v3<0><<<spmmGrid, 256, 0, stream>>>(h1, 128, 128, rowptr, edge_col, edge_val,
                                             nullptr, nullptr, agg2, 128);
    {
        dim3 g(1, (N_NODES + 127) / 128);
        gemm_mfma<1, 0><<<g, 256, 0, stream>>>(agg2, h1, 128, 128, 128, 256, Bt2, 256,
                                               bias2, h2, N_NODES, 128, 128, 1, nullptr);
    }
    // ---- fc1 ----
    {
        dim3 g(1, (N_NODES + 127) / 128);
        gemm_mfma<1, 0><<<g, 256, 0, stream>>>(h2, h2, 128, 128, 128, 128, Btf1, 128,
                                               fc1_b, h3, N_NODES, 128, 128, 1, nullptr);
    }
    // ---- fc2a ----
    {
        dim3 g(2, (N_NODES + 127) / 128);
        gemm_mfma<1, 0><<<g, 256, 0, stream>>>(h3, h3, 128, 128, 128, 128, Btf2a, 128,
                                               fc2a_b, h4, N_NODES, 256, 256, 0, nullptr);
    }
    // ---- batchnorm stats ----
    hipMemsetAsync(stats, 0, 512 * sizeof(float), stream);
    bn_stats<<<256, 256, 0, stream>>>(h4, stats);
    bn_finalize<<<1, 256, 0, stream>>>(stats, bn_g, bn_b);
    // ---- fc2b with fused BN-apply+relu on A ----
    {
        dim3 g(1, (N_NODES + 127) / 128);
        gemm_mfma<0, 1><<<g, 256, 0, stream>>>(h4, h4, 256, 256, 256, 256, Btf2b, 256,
                                               fc2b_b, out, N_NODES, 18, 18, 0, stats);
    }
}

// Round 4
// 657.888 us; speedup vs baseline: 2.2436x; 1.2215x over previous
//
#include <hip/hip_runtime.h>

#define N_NODES 100000
#define N_EDGES 1600000

typedef __attribute__((ext_vector_type(8))) short bf16x8;
typedef __attribute__((ext_vector_type(4))) float f32x4;

__device__ __forceinline__ unsigned short f2bf(float f) {
    unsigned u = __float_as_uint(f);
    u = (u + 0x7FFFu + ((u >> 16) & 1u)) >> 16;
    return (unsigned short)u;
}
__device__ __forceinline__ float bf2f(unsigned short h) {
    return __uint_as_float(((unsigned)h) << 16);
}

// ---------------------------------------------------------------------------
// CSR row_ptr via binary search over sorted edge_row
// ---------------------------------------------------------------------------
__global__ void build_row_ptr(const int* __restrict__ row, int* __restrict__ rp) {
    int n = blockIdx.x * blockDim.x + threadIdx.x;
    if (n > N_NODES) return;
    int lo = 0, hi = N_EDGES;
    while (lo < hi) {
        int mid = (lo + hi) >> 1;
        if (row[mid] < n) lo = mid + 1; else hi = mid;
    }
    rp[n] = lo;
}

// ---------------------------------------------------------------------------
// x (fp32, 100k x 100) -> bf16 padded to ld 104, grid-stride
// ---------------------------------------------------------------------------
__global__ __launch_bounds__(256) void conv_x(const float* __restrict__ x,
                                              unsigned short* __restrict__ xb) {
    const int total = N_NODES * 104;
    for (int i = blockIdx.x * 256 + threadIdx.x; i < total; i += gridDim.x * 256) {
        int r = i / 104, c = i - r * 104;
        xb[i] = (c < 100) ? f2bf(x[(size_t)r * 100 + c]) : (unsigned short)0;
    }
}

// ---------------------------------------------------------------------------
// All weight prep in ONE kernel (flat index over concatenated regions)
// ---------------------------------------------------------------------------
__global__ __launch_bounds__(256) void prep_all(
    const float* __restrict__ gc0W, const float* __restrict__ gc0Ws,
    const float* __restrict__ gc1W, const float* __restrict__ gc1Ws,
    const float* __restrict__ gc2W, const float* __restrict__ gc2Ws,
    const float* __restrict__ f1W,  const float* __restrict__ f2aW,
    const float* __restrict__ f2bW,
    const float* __restrict__ gc0b, const float* __restrict__ gc0bs,
    const float* __restrict__ gc2b, const float* __restrict__ gc2bs,
    unsigned short* __restrict__ Bt0, unsigned short* __restrict__ Bt1,
    unsigned short* __restrict__ Bt2, unsigned short* __restrict__ Btf1,
    unsigned short* __restrict__ Btf2a, unsigned short* __restrict__ Btf2b,
    float* __restrict__ bias0, float* __restrict__ bias2)
{
    int i = blockIdx.x * 256 + threadIdx.x;
    if (i < 44800) {  // Bt0: concat-K (K=100,Kpad=104), N=200, ldk=224
        int n = i / 224, k = i - n * 224; float v = 0.f;
        if (k < 104) { if (k < 100) v = gc0W[(size_t)k * 200 + n]; }
        else { int kr = k - 104; if (kr < 100) v = gc0Ws[(size_t)kr * 200 + n]; }
        Bt0[i] = f2bf(v); return;
    }
    i -= 44800;
    if (i < 57344) {  // Bt1: side-by-side N (K=200, N0=128, N=256), ldk=224
        int n = i / 224, k = i - n * 224; float v = 0.f;
        if (k < 200) v = (n < 128) ? gc1W[(size_t)k * 128 + n] : gc1Ws[(size_t)k * 128 + (n - 128)];
        Bt1[i] = f2bf(v); return;
    }
    i -= 57344;
    if (i < 32768) {  // Bt2: concat-K (K=128), N=128, ldk=256
        int n = i / 256, k = i - n * 256; float v;
        if (k < 128) v = gc2W[(size_t)k * 128 + n];
        else         v = gc2Ws[(size_t)(k - 128) * 128 + n];
        Bt2[i] = f2bf(v); return;
    }
    i -= 32768;
    if (i < 16384) { int n = i >> 7, k = i & 127; Btf1[i] = f2bf(f1W[(size_t)k * 128 + n]); return; }
    i -= 16384;
    if (i < 32768) { int n = i >> 7, k = i & 127; Btf2a[i] = f2bf(f2aW[(size_t)k * 256 + n]); return; }
    i -= 32768;
    if (i < 4608) { int n = i >> 8, k = i & 255; Btf2b[i] = f2bf(f2bW[(size_t)k * 18 + n]); return; }
    i -= 4608;
    if (i < 200) { bias0[i] = gc0b[i] + gc0bs[i]; return; }
    i -= 200;
    if (i < 128) { bias2[i] = gc2b[i] + gc2bs[i]; return; }
}

// ---------------------------------------------------------------------------
// SpMM: one wave per node, lane holds 2 bf16 features, 8 gathers in flight.
// FUSE=1: layer-1 epilogue out = relu(agg + z + b0 + b1), z = xin[node][128+f]
// ---------------------------------------------------------------------------
template<int FUSE>
__global__ __launch_bounds__(256) void spmm_v3(
    const unsigned short* __restrict__ xin, int ldin, int F,
    const int* __restrict__ rp, const int* __restrict__ col,
    const float* __restrict__ val,
    const float* __restrict__ b0, const float* __restrict__ b1,
    unsigned short* __restrict__ outp, int ldout)
{
    int wave = threadIdx.x >> 6, lane = threadIdx.x & 63;
    int node = blockIdx.x * 4 + wave;
    if (node >= N_NODES) return;
    int e0 = rp[node], e1 = rp[node + 1];
    const int f = 2 * lane;
    const bool act = f < F;
    const unsigned short* xbase = xin + f;
    float ax = 0.f, ay = 0.f;
    int e = e0;
    for (; e + 8 <= e1; e += 8) {
        int c[8]; float v[8]; unsigned u[8];
#pragma unroll
        for (int j = 0; j < 8; j++) { c[j] = col[e + j]; v[j] = val[e + j]; }
#pragma unroll
        for (int j = 0; j < 8; j++)
            u[j] = act ? *(const unsigned*)(xbase + (size_t)c[j] * ldin) : 0u;
#pragma unroll
        for (int j = 0; j < 8; j++) {
            ax += v[j] * __uint_as_float(u[j] << 16);
            ay += v[j] * __uint_as_float(u[j] & 0xFFFF0000u);
        }
    }
    for (; e < e1; e++) {
        int c0 = col[e]; float v0 = val[e];
        unsigned u0 = act ? *(const unsigned*)(xbase + (size_t)c0 * ldin) : 0u;
        ax += v0 * __uint_as_float(u0 << 16);
        ay += v0 * __uint_as_float(u0 & 0xFFFF0000u);
    }
    if (act) {
        if (FUSE) {
            unsigned uz = *(const unsigned*)(xin + (size_t)node * ldin + 128 + f);
            float zx = __uint_as_float(uz << 16);
            float zy = __uint_as_float(uz & 0xFFFF0000u);
            ax = fmaxf(ax + zx + b0[f] + b1[f], 0.f);
            ay = fmaxf(ay + zy + b0[f + 1] + b1[f + 1], 0.f);
        }
        unsigned pack = ((unsigned)f2bf(ay) << 16) | (unsigned)f2bf(ax);
        *(unsigned*)(outp + (size_t)node * ldout + f) = pack;
    }
}

// ---------------------------------------------------------------------------
// bf16 MFMA GEMM: C = act(concatK(A0,A1) @ B + bias)
// APPLYBN=1: A elements transformed a = relu(a*sc[k]+sh[k]) at staging
// ---------------------------------------------------------------------------
template<int OUTBF, int APPLYBN>
__global__ __launch_bounds__(256) void gemm_mfma(
    const unsigned short* __restrict__ A0, const unsigned short* __restrict__ A1,
    int lda0, int lda1, int K0, int Ktot,
    const unsigned short* __restrict__ Bt, int ldk,
    const float* __restrict__ bias, void* __restrict__ Cv,
    int M, int N, int ldc, int relu, const float* __restrict__ stats)
{
    __shared__ __align__(16) unsigned short As[128][56];
    __shared__ __align__(16) unsigned short Bs[128][56];

    const int tid = threadIdx.x;
    const int rowBase = blockIdx.y * 128;
    const int colBase = blockIdx.x * 128;
    const int wave = tid >> 6, lane = tid & 63;
    const int wr = (wave >> 1) * 64, wc = (wave & 1) * 64;
    const int lrow = lane & 15, lq = lane >> 4;

    f32x4 acc[4][4] = {};

    for (int kk = 0; kk < ldk; kk += 32) {
#pragma unroll
        for (int i = 0; i < 2; ++i) {
            int c = tid + 256 * i;
            int row = c >> 2;
            int kof = (c & 3) * 8;
            int k0 = kk + kof;
            uint4 av = make_uint4(0, 0, 0, 0);
            int gr = rowBase + row;
            if (gr < M && k0 < Ktot) {
                const unsigned short* src; int krel;
                if (k0 < K0) { src = A0 + (size_t)gr * lda0; krel = k0; }
                else         { src = A1 + (size_t)gr * lda1; krel = k0 - K0; }
                av = *(const uint4*)(src + krel);
                if (APPLYBN) {
                    const float* sc = stats + 512 + k0;
                    const float* sh = stats + 768 + k0;
                    unsigned r[4] = {av.x, av.y, av.z, av.w};
#pragma unroll
                    for (int j = 0; j < 4; j++) {
                        float lo = __uint_as_float(r[j] << 16) * sc[2 * j] + sh[2 * j];
                        float hi = __uint_as_float(r[j] & 0xFFFF0000u) * sc[2 * j + 1] + sh[2 * j + 1];
                        lo = fmaxf(lo, 0.f); hi = fmaxf(hi, 0.f);
                        r[j] = ((unsigned)f2bf(hi) << 16) | (unsigned)f2bf(lo);
                    }
                    av = make_uint4(r[0], r[1], r[2], r[3]);
                }
            }
            *(uint4*)&As[row][kof] = av;
            uint4 bv = make_uint4(0, 0, 0, 0);
            int n0 = colBase + row;
            if (n0 < N) bv = *(const uint4*)(Bt + (size_t)n0 * ldk + k0);
            *(uint4*)&Bs[row][kof] = bv;
        }
        __syncthreads();

        bf16x8 af[4], bfr[4];
#pragma unroll
        for (int m = 0; m < 4; ++m)
            af[m] = *(const bf16x8*)&As[wr + 16 * m + lrow][lq * 8];
#pragma unroll
        for (int n = 0; n < 4; ++n)
            bfr[n] = *(const bf16x8*)&Bs[wc + 16 * n + lrow][lq * 8];
#pragma unroll
        for (int m = 0; m < 4; ++m)
#pragma unroll
            for (int n = 0; n < 4; ++n)
                acc[m][n] = __builtin_amdgcn_mfma_f32_16x16x32_bf16(af[m], bfr[n], acc[m][n], 0, 0, 0);
        __syncthreads();
    }

#pragma unroll
    for (int m = 0; m < 4; ++m) {
#pragma unroll
        for (int n = 0; n < 4; ++n) {
            int colg = colBase + wc + 16 * n + lrow;
            if (colg >= N) continue;
            float bb = bias ? bias[colg] : 0.f;
#pragma unroll
            for (int r = 0; r < 4; ++r) {
                int rowg = rowBase + wr + 16 * m + lq * 4 + r;
                if (rowg >= M) continue;
                float v = acc[m][n][r] + bb;
                if (relu) v = fmaxf(v, 0.f);
                if (OUTBF) ((unsigned short*)Cv)[(size_t)rowg * ldc + colg] = f2bf(v);
                else       ((float*)Cv)[(size_t)rowg * ldc + colg] = v;
            }
        }
    }
}

// ---------------------------------------------------------------------------
// FUSED TAIL: h2 = relu([agg2|h1]@Bt2 + bias2)       (K=256, N=128)
//             h3 = relu(h2@Btf1 + fc1_b)             (K=128, N=128, via LDS)
//             h4 = h3@Btf2a + fc2a_b                 (K=128, N=256, via LDS)
//             + per-block BN column partials -> global atomics
// one block per 128 rows; grid = 782
// ---------------------------------------------------------------------------
__global__ __launch_bounds__(256, 2) void gemm_tail(
    const unsigned short* __restrict__ agg2, const unsigned short* __restrict__ h1,
    const unsigned short* __restrict__ Bt2, const float* __restrict__ bias2,
    const unsigned short* __restrict__ Btf1, const float* __restrict__ fc1b,
    const unsigned short* __restrict__ Btf2a, const float* __restrict__ fc2ab,
    unsigned short* __restrict__ h4, float* __restrict__ stats, int M)
{
    __shared__ __align__(16) unsigned short As[128][56];
    __shared__ __align__(16) unsigned short Bs[256][56];
    __shared__ __align__(16) unsigned short H23[128][136];
    __shared__ float sred[512];

    const int tid = threadIdx.x;
    const int rowBase = blockIdx.x * 128;
    const int wave = tid >> 6, lane = tid & 63;
    const int wr = (wave >> 1) * 64, wc = (wave & 1) * 64;
    const int lrow = lane & 15, lq = lane >> 4;

    // ---------------- stage 1: h2 = relu([agg2|h1]@Bt2 + bias2) ----------------
    {
        f32x4 acc[4][4] = {};
        for (int kk = 0; kk < 256; kk += 32) {
#pragma unroll
            for (int i = 0; i < 2; ++i) {
                int c = tid + 256 * i;
                int row = c >> 2;
                int kof = (c & 3) * 8;
                int k0 = kk + kof;
                uint4 av = make_uint4(0, 0, 0, 0);
                int gr = rowBase + row;
                if (gr < M) {
                    av = (k0 < 128) ? *(const uint4*)(agg2 + (size_t)gr * 128 + k0)
                                    : *(const uint4*)(h1   + (size_t)gr * 128 + (k0 - 128));
                }
                *(uint4*)&As[row][kof] = av;
                *(uint4*)&Bs[row][kof] = *(const uint4*)(Bt2 + (size_t)row * 256 + k0);
            }
            __syncthreads();
            bf16x8 af[4], bfr[4];
#pragma unroll
            for (int m = 0; m < 4; ++m) af[m] = *(const bf16x8*)&As[wr + 16 * m + lrow][lq * 8];
#pragma unroll
            for (int n = 0; n < 4; ++n) bfr[n] = *(const bf16x8*)&Bs[wc + 16 * n + lrow][lq * 8];
#pragma unroll
            for (int m = 0; m < 4; ++m)
#pragma unroll
                for (int n = 0; n < 4; ++n)
                    acc[m][n] = __builtin_amdgcn_mfma_f32_16x16x32_bf16(af[m], bfr[n], acc[m][n], 0, 0, 0);
            __syncthreads();
        }
        // write h2 tile to LDS
#pragma unroll
        for (int n = 0; n < 4; ++n) {
            int colg = wc + 16 * n + lrow;
            float bb = bias2[colg];
#pragma unroll
            for (int m = 0; m < 4; ++m)
#pragma unroll
                for (int r = 0; r < 4; ++r) {
                    int rowl = wr + 16 * m + lq * 4 + r;
                    H23[rowl][colg] = f2bf(fmaxf(acc[m][n][r] + bb, 0.f));
                }
        }
    }
    __syncthreads();

    // ---------------- stage 2: h3 = relu(h2@Btf1 + fc1_b) ----------------
    {
        f32x4 acc[4][4] = {};
        for (int kk = 0; kk < 128; kk += 32) {
#pragma unroll
            for (int i = 0; i < 2; ++i) {
                int c = tid + 256 * i;
                int row = c >> 2;
                int kof = (c & 3) * 8;
                *(uint4*)&Bs[row][kof] = *(const uint4*)(Btf1 + (size_t)row * 128 + kk + kof);
            }
            __syncthreads();
            bf16x8 af[4], bfr[4];
#pragma unroll
            for (int m = 0; m < 4; ++m) af[m] = *(const bf16x8*)&H23[wr + 16 * m + lrow][kk + lq * 8];
#pragma unroll
            for (int n = 0; n < 4; ++n) bfr[n] = *(const bf16x8*)&Bs[wc + 16 * n + lrow][lq * 8];
#pragma unroll
            for (int m = 0; m < 4; ++m)
#pragma unroll
                for (int n = 0; n < 4; ++n)
                    acc[m][n] = __builtin_amdgcn_mfma_f32_16x16x32_bf16(af[m], bfr[n], acc[m][n], 0, 0, 0);
            __syncthreads();
        }
        // overwrite H23 with h3 tile (all reads of h2 completed at last barrier)
#pragma unroll
        for (int n = 0; n < 4; ++n) {
            int colg = wc + 16 * n + lrow;
            float bb = fc1b[colg];
#pragma unroll
            for (int m = 0; m < 4; ++m)
#pragma unroll
                for (int r = 0; r < 4; ++r) {
                    int rowl = wr + 16 * m + lq * 4 + r;
                    H23[rowl][colg] = f2bf(fmaxf(acc[m][n][r] + bb, 0.f));
                }
        }
    }
    __syncthreads();

    // ---------------- stage 3: h4 = h3@Btf2a + fc2a_b (N=256) + BN partials ----
    {
        f32x4 acc[4][8] = {};
        for (int kk = 0; kk < 128; kk += 32) {
#pragma unroll
            for (int i = 0; i < 4; ++i) {
                int c = tid + 256 * i;
                int row = c >> 2;           // 0..255 (n of Btf2a)
                int kof = (c & 3) * 8;
                *(uint4*)&Bs[row][kof] = *(const uint4*)(Btf2a + (size_t)row * 128 + kk + kof);
            }
            __syncthreads();
            bf16x8 af[4], bfr[8];
#pragma unroll
            for (int m = 0; m < 4; ++m) af[m] = *(const bf16x8*)&H23[wr + 16 * m + lrow][kk + lq * 8];
#pragma unroll
            for (int nh = 0; nh < 2; ++nh)
#pragma unroll
                for (int nm = 0; nm < 4; ++nm)
                    bfr[nh * 4 + nm] = *(const bf16x8*)&Bs[128 * nh + wc + 16 * nm + lrow][lq * 8];
#pragma unroll
            for (int m = 0; m < 4; ++m)
#pragma unroll
                for (int n = 0; n < 8; ++n)
                    acc[m][n] = __builtin_amdgcn_mfma_f32_16x16x32_bf16(af[m], bfr[n], acc[m][n], 0, 0, 0);
            __syncthreads();
        }

        // epilogue: h4 store (bf16) + BN column partials
        for (int j = tid; j < 512; j += 256) sred[j] = 0.f;
        __syncthreads();
#pragma unroll
        for (int nh = 0; nh < 2; ++nh)
#pragma unroll
            for (int nm = 0; nm < 4; ++nm) {
                int colg = 128 * nh + wc + 16 * nm + lrow;
                float bb = fc2ab[colg];
                float s = 0.f, s2 = 0.f;
#pragma unroll
                for (int m = 0; m < 4; ++m)
#pragma unroll
                    for (int r = 0; r < 4; ++r) {
                        int rowg = rowBase + wr + 16 * m + lq * 4 + r;
                        if (rowg < M) {
                            float v = acc[m][nh * 4 + nm][r] + bb;
                            h4[(size_t)rowg * 256 + colg] = f2bf(v);
                            s += v; s2 += v * v;
                        }
                    }
                atomicAdd(&sred[colg], s);
                atomicAdd(&sred[256 + colg], s2);
            }
        __syncthreads();
        for (int j = tid; j < 512; j += 256) atomicAdd(&stats[j], sred[j]);
    }
}

__global__ void bn_finalize(float* __restrict__ stats,
                            const float* __restrict__ g,
                            const float* __restrict__ b) {
    int t = threadIdx.x;
    const float invN = 1.f / (float)N_NODES;
    float mu = stats[t] * invN;
    float var = stats[256 + t] * invN - mu * mu;
    float sc = g[t] * rsqrtf(var + 1e-5f);
    stats[512 + t] = sc;
    stats[768 + t] = b[t] - mu * sc;
}

// ---------------------------------------------------------------------------
// launch
// ---------------------------------------------------------------------------
extern "C" void kernel_launch(void* const* d_in, const int* in_sizes, int n_in,
                              void* d_out, int out_size, void* d_ws, size_t ws_size,
                              hipStream_t stream) {
    const float* x        = (const float*)d_in[0];
    const int*   edge_row = (const int*)  d_in[1];
    const int*   edge_col = (const int*)  d_in[2];
    const float* edge_val = (const float*)d_in[3];
    const float* gc0_W  = (const float*)d_in[4];
    const float* gc0_b  = (const float*)d_in[5];
    const float* gc0_Ws = (const float*)d_in[6];
    const float* gc0_bs = (const float*)d_in[7];
    const float* gc1_W  = (const float*)d_in[8];
    const float* gc1_b  = (const float*)d_in[9];
    const float* gc1_Ws = (const float*)d_in[10];
    const float* gc1_bs = (const float*)d_in[11];
    const float* gc2_W  = (const float*)d_in[12];
    const float* gc2_b  = (const float*)d_in[13];
    const float* gc2_Ws = (const float*)d_in[14];
    const float* gc2_bs = (const float*)d_in[15];
    const float* fc1_W  = (const float*)d_in[16];
    const float* fc1_b  = (const float*)d_in[17];
    const float* fc2a_W = (const float*)d_in[18];
    const float* fc2a_b = (const float*)d_in[19];
    const float* bn_g   = (const float*)d_in[20];
    const float* bn_b   = (const float*)d_in[21];
    const float* fc2b_W = (const float*)d_in[22];
    const float* fc2b_b = (const float*)d_in[23];
    float* out = (float*)d_out;

    char* ws = (char*)d_ws;
    int*   rowptr = (int*)ws;                          // 400 KB
    float* stats  = (float*)(ws + 512 * 1024);         // 4 KB
    size_t o = 520 * 1024;
    unsigned short* Bt0   = (unsigned short*)(ws + o); o += 200 * 224 * 2;
    unsigned short* Bt1   = (unsigned short*)(ws + o); o += 256 * 224 * 2;
    unsigned short* Bt2   = (unsigned short*)(ws + o); o += 128 * 256 * 2;
    unsigned short* Btf1  = (unsigned short*)(ws + o); o += 128 * 128 * 2;
    unsigned short* Btf2a = (unsigned short*)(ws + o); o += 256 * 128 * 2;
    unsigned short* Btf2b = (unsigned short*)(ws + o); o += 18 * 256 * 2;
    float* bias0 = (float*)(ws + o); o += 200 * 4;
    float* bias2 = (float*)(ws + o); o += 128 * 4;
    const size_t SLOT = 52u * 1024 * 1024;
    char* S1 = ws + 1 * 1024 * 1024;
    char* S2 = S1 + SLOT;
    char* S3 = S2 + SLOT;

    unsigned short* xb   = (unsigned short*)S1;  // 100k x 104
    unsigned short* agg0 = (unsigned short*)S2;  // 100k x 104
    unsigned short* h0   = (unsigned short*)S3;  // 100k x 200
    unsigned short* yz   = (unsigned short*)S1;  // 100k x 256 (y|z)
    unsigned short* h1   = (unsigned short*)S2;  // 100k x 128
    unsigned short* agg2 = (unsigned short*)S3;  // 100k x 128
    unsigned short* h4   = (unsigned short*)S1;  // 100k x 256

    // ---- prep ----
    build_row_ptr<<<392, 256, 0, stream>>>(edge_row, rowptr);
    conv_x<<<2048, 256, 0, stream>>>(x, xb);
    prep_all<<<(189000 + 255) / 256, 256, 0, stream>>>(
        gc0_W, gc0_Ws, gc1_W, gc1_Ws, gc2_W, gc2_Ws, fc1_W, fc2a_W, fc2b_W,
        gc0_b, gc0_bs, gc2_b, gc2_bs,
        Bt0, Bt1, Bt2, Btf1, Btf2a, Btf2b, bias0, bias2);
    hipMemsetAsync(stats, 0, 512 * sizeof(float), stream);

    const int spmmGrid = (N_NODES + 3) / 4;

    // ---- GC layer 0 ----
    spmm_v3<0><<<spmmGrid, 256, 0, stream>>>(xb, 104, 104, rowptr, edge_col, edge_val,
                                             nullptr, nullptr, agg0, 104);
    {
        dim3 g(2, (N_NODES + 127) / 128);
        gemm_mfma<1, 0><<<g, 256, 0, stream>>>(agg0, xb, 104, 104, 104, 208, Bt0, 224,
                                               bias0, h0, N_NODES, 200, 200, 1, nullptr);
    }
    // ---- GC layer 1 (GEMM-first): yz = h0@[W|Ws]; h1 = relu(SpMM(y)+z+b+bs) ----
    {
        dim3 g(2, (N_NODES + 127) / 128);
        gemm_mfma<1, 0><<<g, 256, 0, stream>>>(h0, h0, 200, 200, 200, 200, Bt1, 224,
                                               nullptr, yz, N_NODES, 256, 256, 0, nullptr);
    }
    spmm_v3<1><<<spmmGrid, 256, 0, stream>>>(yz, 256, 128, rowptr, edge_col, edge_val,
                                             gc1_b, gc1_bs, h1, 128);
    // ---- GC layer 2 SpMM ----
    spmm_v3<0><<<spmmGrid, 256, 0, stream>>>(h1, 128, 128, rowptr, edge_col, edge_val,
                                             nullptr, nullptr, agg2, 128);
    // ---- fused tail: gc2-GEMM + fc1 + fc2a + BN stats ----
    gemm_tail<<<(N_NODES + 127) / 128, 256, 0, stream>>>(
        agg2, h1, Bt2, bias2, Btf1, fc1_b, Btf2a, fc2a_b, h4, stats, N_NODES);
    bn_finalize<<<1, 256, 0, stream>>>(stats, bn_g, bn_b);
    // ---- fc2b with fused BN-apply+relu on A ----
    {
        dim3 g(1, (N_NODES + 127) / 128);
        gemm_mfma<0, 1><<<g, 256, 0, stream>>>(h4, h4, 256, 256, 256, 256, Btf2b, 256,
                                               fc2b_b, out, N_NODES, 18, 18, 0, stats);
    }
}

// Round 5
// 537.888 us; speedup vs baseline: 2.7442x; 1.2231x over previous
//
#include <hip/hip_runtime.h>

#define N_NODES 100000
#define N_EDGES 1600000

typedef __attribute__((ext_vector_type(8))) short bf16x8;
typedef __attribute__((ext_vector_type(4))) float f32x4;

__device__ __forceinline__ unsigned short f2bf(float f) {
    unsigned u = __float_as_uint(f);
    u = (u + 0x7FFFu + ((u >> 16) & 1u)) >> 16;
    return (unsigned short)u;
}
__device__ __forceinline__ float bf2f(unsigned short h) {
    return __uint_as_float(((unsigned)h) << 16);
}
__device__ __forceinline__ float bflo(unsigned w) { return __uint_as_float(w << 16); }
__device__ __forceinline__ float bfhi(unsigned w) { return __uint_as_float(w & 0xFFFF0000u); }

// ---------------------------------------------------------------------------
// CSR row_ptr via binary search over sorted edge_row
// ---------------------------------------------------------------------------
__global__ void build_row_ptr(const int* __restrict__ row, int* __restrict__ rp) {
    int n = blockIdx.x * blockDim.x + threadIdx.x;
    if (n > N_NODES) return;
    int lo = 0, hi = N_EDGES;
    while (lo < hi) {
        int mid = (lo + hi) >> 1;
        if (row[mid] < n) lo = mid + 1; else hi = mid;
    }
    rp[n] = lo;
}

// ---------------------------------------------------------------------------
// x (fp32, 100k x 100) -> bf16 padded to ld 104
// ---------------------------------------------------------------------------
__global__ __launch_bounds__(256) void conv_x(const float* __restrict__ x,
                                              unsigned short* __restrict__ xb) {
    const int total = N_NODES * 104;
    for (int i = blockIdx.x * 256 + threadIdx.x; i < total; i += gridDim.x * 256) {
        int r = i / 104, c = i - r * 104;
        xb[i] = (c < 100) ? f2bf(x[(size_t)r * 100 + c]) : (unsigned short)0;
    }
}

// ---------------------------------------------------------------------------
// All weight prep in ONE kernel
// ---------------------------------------------------------------------------
__global__ __launch_bounds__(256) void prep_all(
    const float* __restrict__ gc0W, const float* __restrict__ gc0Ws,
    const float* __restrict__ gc1W, const float* __restrict__ gc1Ws,
    const float* __restrict__ gc2W, const float* __restrict__ gc2Ws,
    const float* __restrict__ f1W,  const float* __restrict__ f2aW,
    const float* __restrict__ f2bW,
    const float* __restrict__ gc0b, const float* __restrict__ gc0bs,
    const float* __restrict__ gc2b, const float* __restrict__ gc2bs,
    const float* __restrict__ gc1b, const float* __restrict__ gc1bs,
    unsigned short* __restrict__ Bt0, unsigned short* __restrict__ Bt1,
    unsigned short* __restrict__ Bt2, unsigned short* __restrict__ Btf1,
    unsigned short* __restrict__ Btf2a, unsigned short* __restrict__ Btf2b,
    float* __restrict__ bias0, float* __restrict__ bias2, float* __restrict__ bias1)
{
    int i = blockIdx.x * 256 + threadIdx.x;
    if (i < 44800) {  // Bt0: concat-K (K=100,Kpad=104), N=200, ldk=224
        int n = i / 224, k = i - n * 224; float v = 0.f;
        if (k < 104) { if (k < 100) v = gc0W[(size_t)k * 200 + n]; }
        else { int kr = k - 104; if (kr < 100) v = gc0Ws[(size_t)kr * 200 + n]; }
        Bt0[i] = f2bf(v); return;
    }
    i -= 44800;
    if (i < 57344) {  // Bt1: side-by-side N (K=200, N0=128, N=256), ldk=224
        int n = i / 224, k = i - n * 224; float v = 0.f;
        if (k < 200) v = (n < 128) ? gc1W[(size_t)k * 128 + n] : gc1Ws[(size_t)k * 128 + (n - 128)];
        Bt1[i] = f2bf(v); return;
    }
    i -= 57344;
    if (i < 32768) {  // Bt2: concat-K (K=128), N=128, ldk=256
        int n = i / 256, k = i - n * 256; float v;
        if (k < 128) v = gc2W[(size_t)k * 128 + n];
        else         v = gc2Ws[(size_t)(k - 128) * 128 + n];
        Bt2[i] = f2bf(v); return;
    }
    i -= 32768;
    if (i < 16384) { int n = i >> 7, k = i & 127; Btf1[i] = f2bf(f1W[(size_t)k * 128 + n]); return; }
    i -= 16384;
    if (i < 32768) { int n = i >> 7, k = i & 127; Btf2a[i] = f2bf(f2aW[(size_t)k * 256 + n]); return; }
    i -= 32768;
    if (i < 4608) { int n = i >> 8, k = i & 255; Btf2b[i] = f2bf(f2bW[(size_t)k * 18 + n]); return; }
    i -= 4608;
    if (i < 200) { bias0[i] = gc0b[i] + gc0bs[i]; return; }
    i -= 200;
    if (i < 128) { bias2[i] = gc2b[i] + gc2bs[i]; return; }
    i -= 128;
    if (i < 128) { bias1[i] = gc1b[i] + gc1bs[i]; return; }
}

// ---------------------------------------------------------------------------
// SpMM v4: 16 lanes per node (uint4 = 8 features/lane), 4 nodes/wave,
// 4 edges in flight per node. FUSE=1: out = relu(agg + z + b01), z at +128.
// ---------------------------------------------------------------------------
template<int FUSE>
__global__ __launch_bounds__(256) void spmm_v4(
    const unsigned short* __restrict__ xin, int ldin, int F,
    const int* __restrict__ rp, const int* __restrict__ col,
    const float* __restrict__ val, const float* __restrict__ b01,
    unsigned short* __restrict__ outp, int ldout)
{
    const int node = blockIdx.x * 16 + (threadIdx.x >> 4);
    const int l16 = threadIdx.x & 15;
    const int f8 = l16 * 8;
    const bool act = f8 < F;
    const int e0 = rp[node], e1 = rp[node + 1];
    const unsigned short* xf = xin + f8;

    float a[8];
#pragma unroll
    for (int k = 0; k < 8; k++) a[k] = 0.f;

    for (int e = e0; e < e1; e += 4) {
        int   cj[4]; float vj[4];
#pragma unroll
        for (int j = 0; j < 4; j++) {
            int ej = e + j;
            bool m = ej < e1;
            int es = m ? ej : e0;
            cj[j] = col[es];
            float vv = val[es];
            vj[j] = m ? vv : 0.f;
        }
        if (act) {
#pragma unroll
            for (int j = 0; j < 4; j++) {
                uint4 u = *(const uint4*)(xf + (size_t)cj[j] * ldin);
                float v = vj[j];
                a[0] += v * bflo(u.x); a[1] += v * bfhi(u.x);
                a[2] += v * bflo(u.y); a[3] += v * bfhi(u.y);
                a[4] += v * bflo(u.z); a[5] += v * bfhi(u.z);
                a[6] += v * bflo(u.w); a[7] += v * bfhi(u.w);
            }
        }
    }

    if (act) {
        if (FUSE) {
            uint4 uz = *(const uint4*)(xin + (size_t)node * ldin + 128 + f8);
            float z[8] = {bflo(uz.x), bfhi(uz.x), bflo(uz.y), bfhi(uz.y),
                          bflo(uz.z), bfhi(uz.z), bflo(uz.w), bfhi(uz.w)};
#pragma unroll
            for (int k = 0; k < 8; k++)
                a[k] = fmaxf(a[k] + z[k] + b01[f8 + k], 0.f);
        }
        uint4 pk;
        pk.x = ((unsigned)f2bf(a[1]) << 16) | (unsigned)f2bf(a[0]);
        pk.y = ((unsigned)f2bf(a[3]) << 16) | (unsigned)f2bf(a[2]);
        pk.z = ((unsigned)f2bf(a[5]) << 16) | (unsigned)f2bf(a[4]);
        pk.w = ((unsigned)f2bf(a[7]) << 16) | (unsigned)f2bf(a[6]);
        *(uint4*)(outp + (size_t)node * ldout + f8) = pk;
    }
}

// ---------------------------------------------------------------------------
// FUSED HEAD: per 64-row tile:
//   h0 = relu([agg0|xb] @ Bt0 + bias0)   (K=208 pad 224, N=200 pad 256, LDS-resident)
//   yz = h0 @ Bt1                        (K=200 pad 224, N=256)
// Bt1 k>=200 is zero, so h0's pad columns (200..223) may hold garbage.
// ---------------------------------------------------------------------------
__global__ __launch_bounds__(256, 2) void gemm_head(
    const unsigned short* __restrict__ agg0, const unsigned short* __restrict__ xb,
    const unsigned short* __restrict__ Bt0, const float* __restrict__ bias0,
    const unsigned short* __restrict__ Bt1,
    unsigned short* __restrict__ yz, int M)
{
    __shared__ __align__(16) unsigned short As[64][40];
    __shared__ __align__(16) unsigned short Bs[256][40];
    __shared__ __align__(16) unsigned short H[64][232];

    const int tid = threadIdx.x;
    const int rowBase = blockIdx.x * 64;
    const int wave = tid >> 6, lane = tid & 63;
    const int wc = wave * 64;                // wave covers cols wc..wc+63, all 64 rows
    const int lrow = lane & 15, lq = lane >> 4;

    // ---------------- stage 1: h0 tile = relu([agg0|xb]@Bt0 + bias0) ----------
    {
        f32x4 acc[4][4] = {};
        for (int kk = 0; kk < 224; kk += 32) {
            {   // As: 64 rows x 32 k, one uint4/thread
                int row = tid >> 2;
                int kof = (tid & 3) * 8;
                int k0 = kk + kof;
                uint4 av = make_uint4(0, 0, 0, 0);
                int gr = rowBase + row;
                if (gr < M && k0 < 208) {
                    av = (k0 < 104) ? *(const uint4*)(agg0 + (size_t)gr * 104 + k0)
                                    : *(const uint4*)(xb   + (size_t)gr * 104 + (k0 - 104));
                }
                *(uint4*)&As[row][kof] = av;
            }
#pragma unroll
            for (int i = 0; i < 4; ++i) {   // Bs: 256 rows x 32 k
                int c = tid + 256 * i;
                int row = c >> 2;
                int kof = (c & 3) * 8;
                uint4 bv = make_uint4(0, 0, 0, 0);
                if (row < 200) bv = *(const uint4*)(Bt0 + (size_t)row * 224 + kk + kof);
                *(uint4*)&Bs[row][kof] = bv;
            }
            __syncthreads();
            bf16x8 af[4], bfr[4];
#pragma unroll
            for (int m = 0; m < 4; ++m) af[m] = *(const bf16x8*)&As[16 * m + lrow][lq * 8];
#pragma unroll
            for (int n = 0; n < 4; ++n) bfr[n] = *(const bf16x8*)&Bs[wc + 16 * n + lrow][lq * 8];
#pragma unroll
            for (int m = 0; m < 4; ++m)
#pragma unroll
                for (int n = 0; n < 4; ++n)
                    acc[m][n] = __builtin_amdgcn_mfma_f32_16x16x32_bf16(af[m], bfr[n], acc[m][n], 0, 0, 0);
            __syncthreads();
        }
        // write h0 tile into LDS H (cols wc..wc+63); cols >=224 dropped
#pragma unroll
        for (int n = 0; n < 4; ++n) {
            int colg = wc + 16 * n + lrow;
            if (colg >= 224) continue;
            float bb = (colg < 200) ? bias0[colg] : 0.f;
#pragma unroll
            for (int m = 0; m < 4; ++m)
#pragma unroll
                for (int r = 0; r < 4; ++r) {
                    int rowl = 16 * m + lq * 4 + r;
                    H[rowl][colg] = f2bf(fmaxf(acc[m][n][r] + bb, 0.f));
                }
        }
    }
    __syncthreads();

    // ---------------- stage 2: yz tile = h0 @ Bt1 ----------------
    {
        f32x4 acc[4][4] = {};
        for (int kk = 0; kk < 224; kk += 32) {
#pragma unroll
            for (int i = 0; i < 4; ++i) {   // Bs: 256 rows x 32 k from Bt1
                int c = tid + 256 * i;
                int row = c >> 2;
                int kof = (c & 3) * 8;
                *(uint4*)&Bs[row][kof] = *(const uint4*)(Bt1 + (size_t)row * 224 + kk + kof);
            }
            __syncthreads();
            bf16x8 af[4], bfr[4];
#pragma unroll
            for (int m = 0; m < 4; ++m) af[m] = *(const bf16x8*)&H[16 * m + lrow][kk + lq * 8];
#pragma unroll
            for (int n = 0; n < 4; ++n) bfr[n] = *(const bf16x8*)&Bs[wc + 16 * n + lrow][lq * 8];
#pragma unroll
            for (int m = 0; m < 4; ++m)
#pragma unroll
                for (int n = 0; n < 4; ++n)
                    acc[m][n] = __builtin_amdgcn_mfma_f32_16x16x32_bf16(af[m], bfr[n], acc[m][n], 0, 0, 0);
            __syncthreads();
        }
#pragma unroll
        for (int n = 0; n < 4; ++n) {
            int colg = wc + 16 * n + lrow;
#pragma unroll
            for (int m = 0; m < 4; ++m)
#pragma unroll
                for (int r = 0; r < 4; ++r) {
                    int rowg = rowBase + 16 * m + lq * 4 + r;
                    if (rowg < M)
                        yz[(size_t)rowg * 256 + colg] = f2bf(acc[m][n][r]);
                }
        }
    }
}

// ---------------------------------------------------------------------------
// bf16 MFMA GEMM (used for fc2b): C = concatK(A0,A1)@B + bias, APPLYBN on A
// ---------------------------------------------------------------------------
template<int OUTBF, int APPLYBN>
__global__ __launch_bounds__(256) void gemm_mfma(
    const unsigned short* __restrict__ A0, const unsigned short* __restrict__ A1,
    int lda0, int lda1, int K0, int Ktot,
    const unsigned short* __restrict__ Bt, int ldk,
    const float* __restrict__ bias, void* __restrict__ Cv,
    int M, int N, int ldc, int relu, const float* __restrict__ stats)
{
    __shared__ __align__(16) unsigned short As[128][56];
    __shared__ __align__(16) unsigned short Bs[128][56];

    const int tid = threadIdx.x;
    const int rowBase = blockIdx.y * 128;
    const int colBase = blockIdx.x * 128;
    const int wave = tid >> 6, lane = tid & 63;
    const int wr = (wave >> 1) * 64, wc = (wave & 1) * 64;
    const int lrow = lane & 15, lq = lane >> 4;

    f32x4 acc[4][4] = {};

    for (int kk = 0; kk < ldk; kk += 32) {
#pragma unroll
        for (int i = 0; i < 2; ++i) {
            int c = tid + 256 * i;
            int row = c >> 2;
            int kof = (c & 3) * 8;
            int k0 = kk + kof;
            uint4 av = make_uint4(0, 0, 0, 0);
            int gr = rowBase + row;
            if (gr < M && k0 < Ktot) {
                const unsigned short* src; int krel;
                if (k0 < K0) { src = A0 + (size_t)gr * lda0; krel = k0; }
                else         { src = A1 + (size_t)gr * lda1; krel = k0 - K0; }
                av = *(const uint4*)(src + krel);
                if (APPLYBN) {
                    const float* sc = stats + 512 + k0;
                    const float* sh = stats + 768 + k0;
                    unsigned r[4] = {av.x, av.y, av.z, av.w};
#pragma unroll
                    for (int j = 0; j < 4; j++) {
                        float lo = bflo(r[j]) * sc[2 * j] + sh[2 * j];
                        float hi = bfhi(r[j]) * sc[2 * j + 1] + sh[2 * j + 1];
                        lo = fmaxf(lo, 0.f); hi = fmaxf(hi, 0.f);
                        r[j] = ((unsigned)f2bf(hi) << 16) | (unsigned)f2bf(lo);
                    }
                    av = make_uint4(r[0], r[1], r[2], r[3]);
                }
            }
            *(uint4*)&As[row][kof] = av;
            uint4 bv = make_uint4(0, 0, 0, 0);
            int n0 = colBase + row;
            if (n0 < N) bv = *(const uint4*)(Bt + (size_t)n0 * ldk + kk + kof);
            *(uint4*)&Bs[row][kof] = bv;
        }
        __syncthreads();

        bf16x8 af[4], bfr[4];
#pragma unroll
        for (int m = 0; m < 4; ++m) af[m] = *(const bf16x8*)&As[wr + 16 * m + lrow][lq * 8];
#pragma unroll
        for (int n = 0; n < 4; ++n) bfr[n] = *(const bf16x8*)&Bs[wc + 16 * n + lrow][lq * 8];
#pragma unroll
        for (int m = 0; m < 4; ++m)
#pragma unroll
            for (int n = 0; n < 4; ++n)
                acc[m][n] = __builtin_amdgcn_mfma_f32_16x16x32_bf16(af[m], bfr[n], acc[m][n], 0, 0, 0);
        __syncthreads();
    }

#pragma unroll
    for (int m = 0; m < 4; ++m) {
#pragma unroll
        for (int n = 0; n < 4; ++n) {
            int colg = colBase + wc + 16 * n + lrow;
            if (colg >= N) continue;
            float bb = bias ? bias[colg] : 0.f;
#pragma unroll
            for (int r = 0; r < 4; ++r) {
                int rowg = rowBase + wr + 16 * m + lq * 4 + r;
                if (rowg >= M) continue;
                float v = acc[m][n][r] + bb;
                if (relu) v = fmaxf(v, 0.f);
                if (OUTBF) ((unsigned short*)Cv)[(size_t)rowg * ldc + colg] = f2bf(v);
                else       ((float*)Cv)[(size_t)rowg * ldc + colg] = v;
            }
        }
    }
}

// ---------------------------------------------------------------------------
// FUSED TAIL: h2 = relu([agg2|h1]@Bt2 + bias2); h3 = relu(h2@Btf1 + fc1_b);
// h4 = h3@Btf2a + fc2a_b; + BN column partials
// ---------------------------------------------------------------------------
__global__ __launch_bounds__(256, 2) void gemm_tail(
    const unsigned short* __restrict__ agg2, const unsigned short* __restrict__ h1,
    const unsigned short* __restrict__ Bt2, const float* __restrict__ bias2,
    const unsigned short* __restrict__ Btf1, const float* __restrict__ fc1b,
    const unsigned short* __restrict__ Btf2a, const float* __restrict__ fc2ab,
    unsigned short* __restrict__ h4, float* __restrict__ stats, int M)
{
    __shared__ __align__(16) unsigned short As[128][56];
    __shared__ __align__(16) unsigned short Bs[256][56];
    __shared__ __align__(16) unsigned short H23[128][136];
    __shared__ float sred[512];

    const int tid = threadIdx.x;
    const int rowBase = blockIdx.x * 128;
    const int wave = tid >> 6, lane = tid & 63;
    const int wr = (wave >> 1) * 64, wc = (wave & 1) * 64;
    const int lrow = lane & 15, lq = lane >> 4;

    // ---------------- stage 1: h2 = relu([agg2|h1]@Bt2 + bias2) ----------------
    {
        f32x4 acc[4][4] = {};
        for (int kk = 0; kk < 256; kk += 32) {
#pragma unroll
            for (int i = 0; i < 2; ++i) {
                int c = tid + 256 * i;
                int row = c >> 2;
                int kof = (c & 3) * 8;
                int k0 = kk + kof;
                uint4 av = make_uint4(0, 0, 0, 0);
                int gr = rowBase + row;
                if (gr < M) {
                    av = (k0 < 128) ? *(const uint4*)(agg2 + (size_t)gr * 128 + k0)
                                    : *(const uint4*)(h1   + (size_t)gr * 128 + (k0 - 128));
                }
                *(uint4*)&As[row][kof] = av;
                *(uint4*)&Bs[row][kof] = *(const uint4*)(Bt2 + (size_t)row * 256 + k0);
            }
            __syncthreads();
            bf16x8 af[4], bfr[4];
#pragma unroll
            for (int m = 0; m < 4; ++m) af[m] = *(const bf16x8*)&As[wr + 16 * m + lrow][lq * 8];
#pragma unroll
            for (int n = 0; n < 4; ++n) bfr[n] = *(const bf16x8*)&Bs[wc + 16 * n + lrow][lq * 8];
#pragma unroll
            for (int m = 0; m < 4; ++m)
#pragma unroll
                for (int n = 0; n < 4; ++n)
                    acc[m][n] = __builtin_amdgcn_mfma_f32_16x16x32_bf16(af[m], bfr[n], acc[m][n], 0, 0, 0);
            __syncthreads();
        }
#pragma unroll
        for (int n = 0; n < 4; ++n) {
            int colg = wc + 16 * n + lrow;
            float bb = bias2[colg];
#pragma unroll
            for (int m = 0; m < 4; ++m)
#pragma unroll
                for (int r = 0; r < 4; ++r) {
                    int rowl = wr + 16 * m + lq * 4 + r;
                    H23[rowl][colg] = f2bf(fmaxf(acc[m][n][r] + bb, 0.f));
                }
        }
    }
    __syncthreads();

    // ---------------- stage 2: h3 = relu(h2@Btf1 + fc1_b) ----------------
    {
        f32x4 acc[4][4] = {};
        for (int kk = 0; kk < 128; kk += 32) {
#pragma unroll
            for (int i = 0; i < 2; ++i) {
                int c = tid + 256 * i;
                int row = c >> 2;
                int kof = (c & 3) * 8;
                *(uint4*)&Bs[row][kof] = *(const uint4*)(Btf1 + (size_t)row * 128 + kk + kof);
            }
            __syncthreads();
            bf16x8 af[4], bfr[4];
#pragma unroll
            for (int m = 0; m < 4; ++m) af[m] = *(const bf16x8*)&H23[wr + 16 * m + lrow][kk + lq * 8];
#pragma unroll
            for (int n = 0; n < 4; ++n) bfr[n] = *(const bf16x8*)&Bs[wc + 16 * n + lrow][lq * 8];
#pragma unroll
            for (int m = 0; m < 4; ++m)
#pragma unroll
                for (int n = 0; n < 4; ++n)
                    acc[m][n] = __builtin_amdgcn_mfma_f32_16x16x32_bf16(af[m], bfr[n], acc[m][n], 0, 0, 0);
            __syncthreads();
        }
#pragma unroll
        for (int n = 0; n < 4; ++n) {
            int colg = wc + 16 * n + lrow;
            float bb = fc1b[colg];
#pragma unroll
            for (int m = 0; m < 4; ++m)
#pragma unroll
                for (int r = 0; r < 4; ++r) {
                    int rowl = wr + 16 * m + lq * 4 + r;
                    H23[rowl][colg] = f2bf(fmaxf(acc[m][n][r] + bb, 0.f));
                }
        }
    }
    __syncthreads();

    // ---------------- stage 3: h4 = h3@Btf2a + fc2a_b + BN partials ----------
    {
        f32x4 acc[4][8] = {};
        for (int kk = 0; kk < 128; kk += 32) {
#pragma unroll
            for (int i = 0; i < 4; ++i) {
                int c = tid + 256 * i;
                int row = c >> 2;
                int kof = (c & 3) * 8;
                *(uint4*)&Bs[row][kof] = *(const uint4*)(Btf2a + (size_t)row * 128 + kk + kof);
            }
            __syncthreads();
            bf16x8 af[4], bfr[8];
#pragma unroll
            for (int m = 0; m < 4; ++m) af[m] = *(const bf16x8*)&H23[wr + 16 * m + lrow][kk + lq * 8];
#pragma unroll
            for (int nh = 0; nh < 2; ++nh)
#pragma unroll
                for (int nm = 0; nm < 4; ++nm)
                    bfr[nh * 4 + nm] = *(const bf16x8*)&Bs[128 * nh + wc + 16 * nm + lrow][lq * 8];
#pragma unroll
            for (int m = 0; m < 4; ++m)
#pragma unroll
                for (int n = 0; n < 8; ++n)
                    acc[m][n] = __builtin_amdgcn_mfma_f32_16x16x32_bf16(af[m], bfr[n], acc[m][n], 0, 0, 0);
            __syncthreads();
        }

        for (int j = tid; j < 512; j += 256) sred[j] = 0.f;
        __syncthreads();
#pragma unroll
        for (int nh = 0; nh < 2; ++nh)
#pragma unroll
            for (int nm = 0; nm < 4; ++nm) {
                int colg = 128 * nh + wc + 16 * nm + lrow;
                float bb = fc2ab[colg];
                float s = 0.f, s2 = 0.f;
#pragma unroll
                for (int m = 0; m < 4; ++m)
#pragma unroll
                    for (int r = 0; r < 4; ++r) {
                        int rowg = rowBase + wr + 16 * m + lq * 4 + r;
                        if (rowg < M) {
                            float v = acc[m][nh * 4 + nm][r] + bb;
                            h4[(size_t)rowg * 256 + colg] = f2bf(v);
                            s += v; s2 += v * v;
                        }
                    }
                atomicAdd(&sred[colg], s);
                atomicAdd(&sred[256 + colg], s2);
            }
        __syncthreads();
        for (int j = tid; j < 512; j += 256) atomicAdd(&stats[j], sred[j]);
    }
}

__global__ void bn_finalize(float* __restrict__ stats,
                            const float* __restrict__ g,
                            const float* __restrict__ b) {
    int t = threadIdx.x;
    const float invN = 1.f / (float)N_NODES;
    float mu = stats[t] * invN;
    float var = stats[256 + t] * invN - mu * mu;
    float sc = g[t] * rsqrtf(var + 1e-5f);
    stats[512 + t] = sc;
    stats[768 + t] = b[t] - mu * sc;
}

// ---------------------------------------------------------------------------
// launch
// ---------------------------------------------------------------------------
extern "C" void kernel_launch(void* const* d_in, const int* in_sizes, int n_in,
                              void* d_out, int out_size, void* d_ws, size_t ws_size,
                              hipStream_t stream) {
    const float* x        = (const float*)d_in[0];
    const int*   edge_row = (const int*)  d_in[1];
    const int*   edge_col = (const int*)  d_in[2];
    const float* edge_val = (const float*)d_in[3];
    const float* gc0_W  = (const float*)d_in[4];
    const float* gc0_b  = (const float*)d_in[5];
    const float* gc0_Ws = (const float*)d_in[6];
    const float* gc0_bs = (const float*)d_in[7];
    const float* gc1_W  = (const float*)d_in[8];
    const float* gc1_b  = (const float*)d_in[9];
    const float* gc1_Ws = (const float*)d_in[10];
    const float* gc1_bs = (const float*)d_in[11];
    const float* gc2_W  = (const float*)d_in[12];
    const float* gc2_b  = (const float*)d_in[13];
    const float* gc2_Ws = (const float*)d_in[14];
    const float* gc2_bs = (const float*)d_in[15];
    const float* fc1_W  = (const float*)d_in[16];
    const float* fc1_b  = (const float*)d_in[17];
    const float* fc2a_W = (const float*)d_in[18];
    const float* fc2a_b = (const float*)d_in[19];
    const float* bn_g   = (const float*)d_in[20];
    const float* bn_b   = (const float*)d_in[21];
    const float* fc2b_W = (const float*)d_in[22];
    const float* fc2b_b = (const float*)d_in[23];
    float* out = (float*)d_out;

    char* ws = (char*)d_ws;
    int*   rowptr = (int*)ws;                          // 400 KB
    float* stats  = (float*)(ws + 512 * 1024);         // 4 KB
    size_t o = 520 * 1024;
    unsigned short* Bt0   = (unsigned short*)(ws + o); o += 200 * 224 * 2;
    unsigned short* Bt1   = (unsigned short*)(ws + o); o += 256 * 224 * 2;
    unsigned short* Bt2   = (unsigned short*)(ws + o); o += 128 * 256 * 2;
    unsigned short* Btf1  = (unsigned short*)(ws + o); o += 128 * 128 * 2;
    unsigned short* Btf2a = (unsigned short*)(ws + o); o += 256 * 128 * 2;
    unsigned short* Btf2b = (unsigned short*)(ws + o); o += 18 * 256 * 2;
    float* bias0 = (float*)(ws + o); o += 200 * 4;
    float* bias2 = (float*)(ws + o); o += 128 * 4;
    float* bias1 = (float*)(ws + o); o += 128 * 4;
    const size_t SLOT = 52u * 1024 * 1024;
    char* S1 = ws + 1 * 1024 * 1024;
    char* S2 = S1 + SLOT;
    char* S3 = S2 + SLOT;

    unsigned short* xb   = (unsigned short*)S1;  // 100k x 104
    unsigned short* agg0 = (unsigned short*)S2;  // 100k x 104
    unsigned short* yz   = (unsigned short*)S3;  // 100k x 256 (y|z)
    unsigned short* h1   = (unsigned short*)S1;  // 100k x 128 (xb dead)
    unsigned short* agg2 = (unsigned short*)S2;  // 100k x 128 (agg0 dead)
    unsigned short* h4   = (unsigned short*)S3;  // 100k x 256 (yz dead)

    // ---- prep ----
    build_row_ptr<<<392, 256, 0, stream>>>(edge_row, rowptr);
    conv_x<<<2048, 256, 0, stream>>>(x, xb);
    prep_all<<<(189128 + 255) / 256, 256, 0, stream>>>(
        gc0_W, gc0_Ws, gc1_W, gc1_Ws, gc2_W, gc2_Ws, fc1_W, fc2a_W, fc2b_W,
        gc0_b, gc0_bs, gc2_b, gc2_bs, gc1_b, gc1_bs,
        Bt0, Bt1, Bt2, Btf1, Btf2a, Btf2b, bias0, bias2, bias1);
    hipMemsetAsync(stats, 0, 512 * sizeof(float), stream);

    const int spmmGrid = N_NODES / 16;  // 6250, exact

    // ---- GC layer 0 SpMM ----
    spmm_v4<0><<<spmmGrid, 256, 0, stream>>>(xb, 104, 104, rowptr, edge_col, edge_val,
                                             nullptr, agg0, 104);
    // ---- fused head: L0-GEMM + L1-GEMM -> yz ----
    gemm_head<<<(N_NODES + 63) / 64, 256, 0, stream>>>(agg0, xb, Bt0, bias0, Bt1, yz, N_NODES);
    // ---- layer-1 SpMM on y + fused combine -> h1 ----
    spmm_v4<1><<<spmmGrid, 256, 0, stream>>>(yz, 256, 128, rowptr, edge_col, edge_val,
                                             bias1, h1, 128);
    // ---- GC layer 2 SpMM ----
    spmm_v4<0><<<spmmGrid, 256, 0, stream>>>(h1, 128, 128, rowptr, edge_col, edge_val,
                                             nullptr, agg2, 128);
    // ---- fused tail: gc2-GEMM + fc1 + fc2a + BN stats ----
    gemm_tail<<<(N_NODES + 127) / 128, 256, 0, stream>>>(
        agg2, h1, Bt2, bias2, Btf1, fc1_b, Btf2a, fc2a_b, h4, stats, N_NODES);
    bn_finalize<<<1, 256, 0, stream>>>(stats, bn_g, bn_b);
    // ---- fc2b with fused BN-apply+relu on A ----
    {
        dim3 g(1, (N_NODES + 127) / 128);
        gemm_mfma<0, 1><<<g, 256, 0, stream>>>(h4, h4, 256, 256, 256, 256, Btf2b, 256,
                                               fc2b_b, out, N_NODES, 18, 18, 0, stats);
    }
}